// Round 12
// baseline (2432.118 us; speedup 1.0000x reference)
//
#include <hip/hip_runtime.h>
#include <math.h>

// ---------------- problem constants (fixed by setup_inputs) ----------------
#define N_    256
#define T_    36
#define M_    50
#define P_    80
#define K_    161          // 1 + 2P
#define LKC   6            // k-elements per lane (32 lanes per column)
#define LSTR  8            // padded LDS stride per lane (float4+float2 reads)
#define DROW  256          // floats per t-row in LDS (32 lanes * 8)
#define NBR   800          // 800 blocks * 4 waves * 4 cols = 12800 columns
#define NTR   256          // 4 waves/block
#define LAM_  0.1f
#define MAXIT 100

#define KM_     (K_*M_)        // 8050
#define TM_     (T_*M_)        // 1800
#define OUT_DIC 2060800        // N*K*M
#define OUT_REC 2066596        // + T*K

// ---- workspace float offsets ----
#define WS_LINV 0
#define WS_D    64             // 36*256 = 9216 floats (padded [t][32][8])
#define WS_ACC  9472           // 2 passes * 100 iters * 4 slots = 800 floats
#define WS_WN   10272          // 1 float (sum of wn^2 over pass-1 code)
#define WS_NIT1 10274          // int slot: pass-1 replay count (101 = none)
#define WS_NIT2 10275          // int slot: pass-2 replay count

// ---------------------------------------------------------------------------
// kernel 1: dictionary output + Linv + padded-D table in ws
// ---------------------------------------------------------------------------
__global__ __launch_bounds__(256) void k_dict(const float* __restrict__ rr,
                                              const float* __restrict__ th,
                                              float* __restrict__ out,
                                              float* __restrict__ ws) {
    __shared__ float Dl[T_*K_];
    const int tid = threadIdx.x;
    for (int e = tid; e < T_*K_; e += 256) {
        int t = e / K_, k = e - (e / K_) * K_;
        float v;
        if (k == 0) v = 1.f;
        else if (k <= P_)      { float r = rr[k-1];     float a = th[k-1]*(float)t;
                                 v = powf(r, (float)t) * cosf(a); }
        else                   { float r = rr[k-1-P_];  float a = th[k-1-P_]*(float)t;
                                 v = powf(r, (float)t) * sinf(a); }
        Dl[e] = v;
        out[OUT_DIC + t*K_ + k] = v;
    }
    __syncthreads();
    // padded ws copy: ws[WS_D + t*256 + sub*8 + j] = D[t][sub*6+j] (j<6,k<K)
    for (int e = tid; e < T_*DROW; e += 256) {
        int t = e >> 8, s = e & 255;
        int sub = s >> 3, j = s & 7;
        int kg = sub*LKC + j;
        ws[WS_D + e] = (j < LKC && kg < K_) ? Dl[t*K_ + kg] : 0.f;
    }
    float loc = 0.f;
    for (int e = tid; e < T_*T_; e += 256) {
        int t1 = e / T_, t2 = e - (e / T_) * T_;
        float s = 0.f;
        for (int k = 0; k < K_; ++k) s = fmaf(Dl[t1*K_+k], Dl[t2*K_+k], s);
        loc = fmaf(s, s, loc);
    }
    #pragma unroll
    for (int mm = 1; mm < 64; mm <<= 1) loc += __shfl_xor(loc, mm);
    __shared__ float rb[4];
    if ((tid & 63) == 0) rb[tid >> 6] = loc;
    __syncthreads();
    if (tid == 0) {
        float tot = rb[0] + rb[1] + rb[2] + rb[3];
        ws[WS_LINV] = 1.0f / sqrtf(tot);   // 1/frob(DtD) via frob(D D^T)
    }
}

// ---- 32-lane sum: 4 DPP levels + one xor-16 swizzle ------------------------
template<int CTRL>
__device__ __forceinline__ float dpp_mov(float v) {
    int p = __builtin_amdgcn_update_dpp(0, __float_as_int(v), CTRL, 0xF, 0xF, true);
    return __int_as_float(p);
}
__device__ __forceinline__ float reduce16v(float z) {
    z += dpp_mov<0xB1>(z);     // quad_perm xor1
    z += dpp_mov<0x4E>(z);     // quad_perm xor2
    z += dpp_mov<0x141>(z);    // row_half_mirror
    z += dpp_mov<0x140>(z);    // row_mirror -> 16-lane sums
    return z;
}
__device__ __forceinline__ float reduce32v(float z) {
    z = reduce16v(z);
    z += __shfl_xor(z, 16);
    return z;
}

// per-thread geometry
struct Geo { int n0, m0, n1, m1, sub, lane, gw, lofs; };
__device__ __forceinline__ Geo make_geo() {
    Geo g;
    const int tid = threadIdx.x;
    g.lane = tid & 63;
    g.sub  = g.lane & 31;
    g.gw   = (int)blockIdx.x * (NTR/64) + (tid >> 6);
    const int colb = g.gw*4 + (g.lane >> 5)*2;     // [0, 12800), 2 cols/thread
    g.n0 = colb / M_;       g.m0 = colb - g.n0*M_;
    g.n1 = (colb+1) / M_;   g.m1 = (colb+1) - g.n1*M_;
    g.lofs = g.sub * LSTR;
    return g;
}

// ---------------------------------------------------------------------------
// k_run<PASS>: one reweighting pass, MAXIT iters, conv norms, code write.
// 32 lanes/col, KC=6, C=2: state x,y,cm,cp[2][6]=48 + u 12 + D 6 ~= 75 live
// floats -> fits under the RA's observed ~100-reg ceiling (r7-r11 evidence).
// Padded D rows: 2 LDS instr/t (b128+b64) = 72/wave-iter (vs 108 at KC=12).
// PASS 0: scalar wl = lam*Linv. PASS 1: cm/cp = b -/+ wl(x1) precomputed.
// ---------------------------------------------------------------------------
template<int PASS>
__global__ __attribute__((amdgpu_flat_work_group_size(NTR, NTR),
                          amdgpu_waves_per_eu(2, 3)))
void k_run(const float* __restrict__ X,
           float* __restrict__ out,
           float* __restrict__ ws) {
    __shared__ __align__(16) float Dl[T_*DROW];
    const int tid = threadIdx.x;
    for (int e = tid; e < T_*DROW; e += NTR) Dl[e] = ws[WS_D + e];
    const float Linv = ws[WS_LINV];
    __syncthreads();

    Geo g = make_geo();
    const float* Y0 = X + g.n0*TM_ + g.m0;
    const float* Y1 = X + g.n1*TM_ + g.m1;

    float x[2][LKC], y[2][LKC], cm[2][LKC], cp[2][LKC];
    const float wlc = LAM_ * Linv;

    // ---- b = Linv * (D^T Ycol), stored into cm ----
    #pragma unroll
    for (int j = 0; j < LKC; ++j) { cm[0][j] = 0.f; cm[1][j] = 0.f; }
    #pragma unroll 2
    for (int t = 0; t < T_; ++t) {
        float yv0 = Y0[t*M_], yv1 = Y1[t*M_];
        const float* dr = Dl + t*DROW + g.lofs;
        float4 d01 = *(const float4*)dr;
        float2 d2  = *(const float2*)(dr + 4);
        float da[LKC] = {d01.x, d01.y, d01.z, d01.w, d2.x, d2.y};
        #pragma unroll
        for (int j = 0; j < LKC; ++j) {
            cm[0][j] = fmaf(da[j], yv0, cm[0][j]);
            cm[1][j] = fmaf(da[j], yv1, cm[1][j]);
        }
    }
    #pragma unroll
    for (int j = 0; j < LKC; ++j) { cm[0][j] *= Linv; cm[1][j] *= Linv; }

    if (PASS == 1) {
        // wl = K*lam*Linv/||wn|| * 1/(|x1|+0.01); cm=b-wl, cp=b+wl
        float scale = ((float)K_) * (LAM_ * Linv) / sqrtf(ws[WS_WN]);
        #pragma unroll
        for (int c = 0; c < 2; ++c) {
            const int nn = c ? g.n1 : g.n0, mm2 = c ? g.m1 : g.m0;
            #pragma unroll
            for (int j = 0; j < LKC; ++j) {
                int kg = g.sub*LKC + j;
                float x1 = (kg < K_) ? out[nn*KM_ + kg*M_ + mm2] : 0.f;
                float wl = scale / (fabsf(x1) + 0.01f);
                float bb = cm[c][j];
                cm[c][j] = bb - wl;
                cp[c][j] = bb + wl;
            }
        }
    }

    float tcur = 1.f;

    auto iterate = [&](float tt) -> float {
        float u[2][LKC];
        #pragma unroll
        for (int j = 0; j < LKC; ++j) { u[0][j] = 0.f; u[1][j] = 0.f; }
        #pragma unroll 2
        for (int t = 0; t < T_; ++t) {
            const float* dr = Dl + t*DROW + g.lofs;
            float4 d01 = *(const float4*)dr;
            float2 d2  = *(const float2*)(dr + 4);
            float da[LKC] = {d01.x, d01.y, d01.z, d01.w, d2.x, d2.y};
            float z0 = 0.f, z1 = 0.f;
            #pragma unroll
            for (int j = 0; j < LKC; ++j) {
                z0 = fmaf(da[j], y[0][j], z0);
                z1 = fmaf(da[j], y[1][j], z1);
            }
            z0 = reduce32v(z0);                    // all 32 lanes hold z_t
            z1 = reduce32v(z1);
            #pragma unroll
            for (int j = 0; j < LKC; ++j) {
                u[0][j] = fmaf(da[j], z0, u[0][j]);
                u[1][j] = fmaf(da[j], z1, u[1][j]);
            }
        }
        float ss = 0.f;
        #pragma unroll
        for (int c = 0; c < 2; ++c) {
            #pragma unroll
            for (int j = 0; j < LKC; ++j) {
                float v = fmaf(-Linv, u[c][j], y[c][j]);   // Ay
                float xn;
                if (PASS == 0) {
                    float s = v + cm[c][j];                 // Ay + b
                    xn = fmaxf(0.f, s - wlc) + fminf(0.f, s + wlc);
                } else {
                    xn = fmaxf(0.f, v + cm[c][j]) + fminf(0.f, v + cp[c][j]);
                }
                float d = xn - x[c][j];
                ss      = fmaf(d, d, ss);
                y[c][j] = fmaf(tt, d, xn);
                x[c][j] = xn;
            }
        }
        return ss;
    };

    #pragma unroll
    for (int j = 0; j < LKC; ++j) {
        x[0][j] = 0.f; x[1][j] = 0.f; y[0][j] = 0.f; y[1][j] = 0.f;
    }
    float* acc = ws + WS_ACC + PASS*4*MAXIT;
    for (int i = 0; i < MAXIT; ++i) {
        float tnext = 0.5f * (1.f + sqrtf(fmaf(4.f*tcur, tcur, 1.f)));
        float tt = (tcur - 1.f) / tnext;
        tcur = tnext;
        float ss = iterate(tt);
        ss = reduce16v(ss);
        ss += __shfl_xor(ss, 16);
        ss += __shfl_xor(ss, 32);
        if (g.lane == 0) atomicAdd(acc + i*4 + (g.gw & 3), ss);
    }

    // ---- write code ----
    #pragma unroll
    for (int j = 0; j < LKC; ++j) {
        int kg = g.sub*LKC + j;
        if (kg < K_) {
            out[g.n0*KM_ + kg*M_ + g.m0] = x[0][j];
            out[g.n1*KM_ + kg*M_ + g.m1] = x[1][j];
        }
    }
}

// ---------------------------------------------------------------------------
// helpers for the (rarely-executed) replay/finish kernels
// ---------------------------------------------------------------------------
__device__ __forceinline__ void compute_b(const float* Dl, int lofs, float Linv,
                                          const float* Y0, const float* Y1,
                                          float (&b)[2][LKC]) {
    #pragma unroll
    for (int j = 0; j < LKC; ++j) { b[0][j] = 0.f; b[1][j] = 0.f; }
    #pragma unroll 2
    for (int t = 0; t < T_; ++t) {
        float yv0 = Y0[t*M_], yv1 = Y1[t*M_];
        const float* dr = Dl + t*DROW + lofs;
        float4 d01 = *(const float4*)dr;
        float2 d2  = *(const float2*)(dr + 4);
        float da[LKC] = {d01.x, d01.y, d01.z, d01.w, d2.x, d2.y};
        #pragma unroll
        for (int j = 0; j < LKC; ++j) {
            b[0][j] = fmaf(da[j], yv0, b[0][j]);
            b[1][j] = fmaf(da[j], yv1, b[1][j]);
        }
    }
    #pragma unroll
    for (int j = 0; j < LKC; ++j) { b[0][j] *= Linv; b[1][j] *= Linv; }
}

__device__ __forceinline__ void run_fista(const float* Dl, int lofs, float Linv,
                                          const float (&cmv)[2][LKC],
                                          const float (&cpv)[2][LKC],
                                          float (&x)[2][LKC], int nit) {
    float y[2][LKC];
    #pragma unroll
    for (int j = 0; j < LKC; ++j) {
        x[0][j] = 0.f; x[1][j] = 0.f; y[0][j] = 0.f; y[1][j] = 0.f;
    }
    float tcur = 1.f;
    for (int i = 0; i < nit; ++i) {
        float tnext = 0.5f * (1.f + sqrtf(fmaf(4.f*tcur, tcur, 1.f)));
        float tt = (tcur - 1.f) / tnext;
        tcur = tnext;
        float u[2][LKC];
        #pragma unroll
        for (int j = 0; j < LKC; ++j) { u[0][j] = 0.f; u[1][j] = 0.f; }
        #pragma unroll 2
        for (int t = 0; t < T_; ++t) {
            const float* dr = Dl + t*DROW + lofs;
            float4 d01 = *(const float4*)dr;
            float2 d2  = *(const float2*)(dr + 4);
            float da[LKC] = {d01.x, d01.y, d01.z, d01.w, d2.x, d2.y};
            float z0 = 0.f, z1 = 0.f;
            #pragma unroll
            for (int j = 0; j < LKC; ++j) {
                z0 = fmaf(da[j], y[0][j], z0);
                z1 = fmaf(da[j], y[1][j], z1);
            }
            z0 = reduce32v(z0);
            z1 = reduce32v(z1);
            #pragma unroll
            for (int j = 0; j < LKC; ++j) {
                u[0][j] = fmaf(da[j], z0, u[0][j]);
                u[1][j] = fmaf(da[j], z1, u[1][j]);
            }
        }
        #pragma unroll
        for (int c = 0; c < 2; ++c) {
            #pragma unroll
            for (int j = 0; j < LKC; ++j) {
                float v = fmaf(-Linv, u[c][j], y[c][j]);
                float xn = fmaxf(0.f, v + cmv[c][j]) + fminf(0.f, v + cpv[c][j]);
                float d = xn - x[c][j];
                y[c][j] = fmaf(tt, d, xn);
                x[c][j] = xn;
            }
        }
    }
}

__device__ __forceinline__ void write_code_g(const Geo& g, const float (&x)[2][LKC],
                                             float* out) {
    #pragma unroll
    for (int j = 0; j < LKC; ++j) {
        int kg = g.sub*LKC + j;
        if (kg < K_) {
            out[g.n0*KM_ + kg*M_ + g.m0] = x[0][j];
            out[g.n1*KM_ + kg*M_ + g.m1] = x[1][j];
        }
    }
}
__device__ __forceinline__ void load_code_g(const Geo& g, float (&x)[2][LKC],
                                            const float* out) {
    #pragma unroll
    for (int j = 0; j < LKC; ++j) {
        int kg = g.sub*LKC + j;
        x[0][j] = (kg < K_) ? out[g.n0*KM_ + kg*M_ + g.m0] : 0.f;
        x[1][j] = (kg < K_) ? out[g.n1*KM_ + kg*M_ + g.m1] : 0.f;
    }
}

// ---------------------------------------------------------------------------
// k_scan: find first iter with global ||dx||^2 < (tol*K)^2 (4 slots per iter)
// ---------------------------------------------------------------------------
__global__ void k_scan(float* __restrict__ ws, int pass) {
    const float THR2 = (1e-5f * (float)K_) * (1e-5f * (float)K_);
    int lane = threadIdx.x;
    const float* acc = ws + WS_ACC + pass*4*MAXIT;
    int best = MAXIT + 1;
    for (int i = lane; i < MAXIT; i += 64) {
        float a = (acc[i*4] + acc[i*4+1]) + (acc[i*4+2] + acc[i*4+3]);
        if (a < THR2) best = min(best, i + 1);
    }
    #pragma unroll
    for (int mm = 1; mm < 64; mm <<= 1) best = min(best, __shfl_xor(best, mm));
    if (lane == 0) ((int*)ws)[pass == 0 ? WS_NIT1 : WS_NIT2] = best;
}

// ---------------------------------------------------------------------------
// k_fin1: if pass-1 converged early, replay nit1 iters and rewrite code;
// then accumulate ||wn||^2 into WS_WN. (Expected: no replay -> cheap.)
// ---------------------------------------------------------------------------
__global__ __launch_bounds__(NTR, 1) void k_fin1(const float* __restrict__ X,
                                                 float* __restrict__ out,
                                                 float* __restrict__ ws) {
    __shared__ __align__(16) float Dl[T_*DROW];
    for (int e = threadIdx.x; e < T_*DROW; e += NTR) Dl[e] = ws[WS_D + e];
    const float Linv = ws[WS_LINV];
    __syncthreads();

    Geo g = make_geo();
    const int nit1 = ((const int*)ws)[WS_NIT1];
    float x[2][LKC];

    if (nit1 <= MAXIT) {
        float b[2][LKC], cmv[2][LKC], cpv[2][LKC];
        compute_b(Dl, g.lofs, Linv, X + g.n0*TM_ + g.m0, X + g.n1*TM_ + g.m1, b);
        const float wlc = LAM_ * Linv;
        #pragma unroll
        for (int c = 0; c < 2; ++c)
            #pragma unroll
            for (int j = 0; j < LKC; ++j) { cmv[c][j] = b[c][j] - wlc;
                                            cpv[c][j] = b[c][j] + wlc; }
        run_fista(Dl, g.lofs, Linv, cmv, cpv, x, nit1);
        write_code_g(g, x, out);
    } else {
        load_code_g(g, x, out);
    }

    float loc = 0.f;
    #pragma unroll
    for (int c = 0; c < 2; ++c)
        #pragma unroll
        for (int j = 0; j < LKC; ++j) {
            if (g.sub*LKC + j < K_) {
                float wn = 1.0f / (fabsf(x[c][j]) + 0.01f);
                loc = fmaf(wn, wn, loc);
            }
        }
    #pragma unroll
    for (int mm = 1; mm < 64; mm <<= 1) loc += __shfl_xor(loc, mm);
    if (g.lane == 0) atomicAdd(ws + WS_WN, loc);
}

// ---------------------------------------------------------------------------
// k_fin2: if pass-2 converged early, re-derive pass-1 x, recompute weights,
// replay nit2 iters, rewrite code. Always write reconst from final code.
// ---------------------------------------------------------------------------
__global__ __launch_bounds__(NTR, 1) void k_fin2(const float* __restrict__ X,
                                                 float* __restrict__ out,
                                                 float* __restrict__ ws) {
    __shared__ __align__(16) float Dl[T_*DROW];
    for (int e = threadIdx.x; e < T_*DROW; e += NTR) Dl[e] = ws[WS_D + e];
    const float Linv = ws[WS_LINV];
    __syncthreads();

    Geo g = make_geo();
    const int nit1 = ((const int*)ws)[WS_NIT1];
    const int nit2 = ((const int*)ws)[WS_NIT2];
    float x[2][LKC];

    if (nit2 <= MAXIT) {
        float b[2][LKC], cmv[2][LKC], cpv[2][LKC];
        compute_b(Dl, g.lofs, Linv, X + g.n0*TM_ + g.m0, X + g.n1*TM_ + g.m1, b);
        const float wlc = LAM_ * Linv;
        #pragma unroll
        for (int c = 0; c < 2; ++c)
            #pragma unroll
            for (int j = 0; j < LKC; ++j) { cmv[c][j] = b[c][j] - wlc;
                                            cpv[c][j] = b[c][j] + wlc; }
        int nrep1 = nit1 <= MAXIT ? nit1 : MAXIT;
        run_fista(Dl, g.lofs, Linv, cmv, cpv, x, nrep1);
        float scale = ((float)K_) * (LAM_ * Linv) / sqrtf(ws[WS_WN]);
        #pragma unroll
        for (int c = 0; c < 2; ++c)
            #pragma unroll
            for (int j = 0; j < LKC; ++j) {
                float wl = scale / (fabsf(x[c][j]) + 0.01f);
                cmv[c][j] = b[c][j] - wl;
                cpv[c][j] = b[c][j] + wl;
            }
        run_fista(Dl, g.lofs, Linv, cmv, cpv, x, nit2);
        write_code_g(g, x, out);
    } else {
        load_code_g(g, x, out);
    }

    // ---- reconst = D @ code ----
    #pragma unroll 2
    for (int t = 0; t < T_; ++t) {
        const float* dr = Dl + t*DROW + g.lofs;
        float4 d01 = *(const float4*)dr;
        float2 d2  = *(const float2*)(dr + 4);
        float da[LKC] = {d01.x, d01.y, d01.z, d01.w, d2.x, d2.y};
        float z0 = 0.f, z1 = 0.f;
        #pragma unroll
        for (int j = 0; j < LKC; ++j) {
            z0 = fmaf(da[j], x[0][j], z0);
            z1 = fmaf(da[j], x[1][j], z1);
        }
        z0 = reduce32v(z0);
        z1 = reduce32v(z1);
        if (g.sub == (t & 31)) {
            out[OUT_REC + g.n0*TM_ + t*M_ + g.m0] = z0;
            out[OUT_REC + g.n1*TM_ + t*M_ + g.m1] = z1;
        }
    }
}

// ---------------------------------------------------------------------------
extern "C" void kernel_launch(void* const* d_in, const int* in_sizes, int n_in,
                              void* d_out, int out_size, void* d_ws, size_t ws_size,
                              hipStream_t stream) {
    const float* X  = (const float*)d_in[0];
    const float* rr = (const float*)d_in[1];
    const float* th = (const float*)d_in[2];
    float* out = (float*)d_out;
    float* ws  = (float*)d_ws;

    // zero conv accumulators + wn accumulator + niter slots (every call)
    hipMemsetAsync((char*)d_ws + WS_ACC*sizeof(float), 0, 4096, stream);
    k_dict  <<<dim3(1),   dim3(256), 0, stream>>>(rr, th, out, ws);
    k_run<0><<<dim3(NBR), dim3(NTR), 0, stream>>>(X, out, ws);
    k_scan  <<<dim3(1),   dim3(64),  0, stream>>>(ws, 0);
    k_fin1  <<<dim3(NBR), dim3(NTR), 0, stream>>>(X, out, ws);
    k_run<1><<<dim3(NBR), dim3(NTR), 0, stream>>>(X, out, ws);
    k_scan  <<<dim3(1),   dim3(64),  0, stream>>>(ws, 1);
    k_fin2  <<<dim3(NBR), dim3(NTR), 0, stream>>>(X, out, ws);
}

// Round 13
// 2132.306 us; speedup vs baseline: 1.1406x; 1.1406x over previous
//
#include <hip/hip_runtime.h>
#include <math.h>

// ---------------- problem constants (fixed by setup_inputs) ----------------
#define N_    256
#define T_    36
#define M_    50
#define P_    80
#define K_    161          // 1 + 2P
#define PADK  192          // K padded to 16*12, pad cols are zero
#define KC    12           // k-elements per lane (16 lanes per column)
#define NBR   800          // 800 blocks * 2 waves * 4 cols * C=2 -> 12800 cols
#define NTR   128          // 2 waves/block (r7 geometry: best measured)
#define LAM_  0.1f
#define MAXIT 100

#define KM_     (K_*M_)        // 8050
#define TM_     (T_*M_)        // 1800
#define OUT_DIC 2060800        // N*K*M
#define OUT_REC 2066596        // + T*K

// ---- workspace float offsets ----
#define WS_LINV 0
#define WS_D    64             // 36*192 = 6912 floats
#define WS_ACC  8192           // 2 passes * 100 iters * 4 slots = 800 floats
#define WS_WN   9000           // 1 float (sum of wn^2 over pass-1 code)
#define WS_NIT1 9002           // int slot: pass-1 replay count (101 = none)
#define WS_NIT2 9003           // int slot: pass-2 replay count

// ---------------------------------------------------------------------------
// kernel 1: build dictionary (write dic output + padded D to ws) and
// Linv = 1/frob(DtD) using frob(DtD) == frob(D D^T)  (36x36 instead of 161^2)
// ---------------------------------------------------------------------------
__global__ __launch_bounds__(256) void k_dict(const float* __restrict__ rr,
                                              const float* __restrict__ th,
                                              float* __restrict__ out,
                                              float* __restrict__ ws) {
    __shared__ float Dl[T_*PADK];
    const int tid = threadIdx.x;
    for (int e = tid; e < T_*PADK; e += 256) {
        int t = e / PADK, k = e - (e / PADK) * PADK;
        float v = 0.f;
        if (k == 0) v = 1.f;
        else if (k <= P_)      { float r = rr[k-1];     float a = th[k-1]*(float)t;
                                 v = powf(r, (float)t) * cosf(a); }
        else if (k <= 2*P_)    { float r = rr[k-1-P_];  float a = th[k-1-P_]*(float)t;
                                 v = powf(r, (float)t) * sinf(a); }
        Dl[e] = v;
        ws[WS_D + e] = v;
        if (k < K_) out[OUT_DIC + t*K_ + k] = v;
    }
    __syncthreads();
    float loc = 0.f;
    for (int e = tid; e < T_*T_; e += 256) {
        int t1 = e / T_, t2 = e - (e / T_) * T_;
        float s = 0.f;
        for (int k = 0; k < K_; ++k) s = fmaf(Dl[t1*PADK+k], Dl[t2*PADK+k], s);
        loc = fmaf(s, s, loc);
    }
    #pragma unroll
    for (int mm = 1; mm < 64; mm <<= 1) loc += __shfl_xor(loc, mm);
    __shared__ float rb[4];
    if ((tid & 63) == 0) rb[tid >> 6] = loc;
    __syncthreads();
    if (tid == 0) {
        float tot = rb[0] + rb[1] + rb[2] + rb[3];
        ws[WS_LINV] = 1.0f / sqrtf(tot);
    }
}

// ---- DPP-based 16-lane sum (pure VALU, off the LDS pipe) -------------------
template<int CTRL>
__device__ __forceinline__ float dpp_mov(float v) {
    int p = __builtin_amdgcn_update_dpp(0, __float_as_int(v), CTRL, 0xF, 0xF, true);
    return __int_as_float(p);
}
__device__ __forceinline__ float reduce16(float z) {
    z += dpp_mov<0xB1>(z);     // quad_perm [1,0,3,2]  (xor 1)
    z += dpp_mov<0x4E>(z);     // quad_perm [2,3,0,1]  (xor 2)
    z += dpp_mov<0x141>(z);    // row_half_mirror      (other quad)
    z += dpp_mov<0x140>(z);    // row_mirror           (other 8-group)
    return z;
}

// ---------------------------------------------------------------------------
// k_run<PASS>: r7's winning kernel (C=2, KC=12, NTR=128, waves_per_eu(1,2))
// with ONE change: the loop-invariant shrink constants cm/cp (48 floats of
// register state) move to LDS in SoA layout [2*KC][NTR] (lane->bank stride 1,
// 2-way aliasing = free). Hot reg state drops to y24+u24+x24+da12 ~= 95,
// which fits the 88-108 arch VGPRs the RA grants -> accvgpr churn gone.
// PASS 0: SCM holds b, scalar wl. PASS 1: SCM/SCP = b -/+ wl(x1).
// ---------------------------------------------------------------------------
template<int PASS>
__global__ __attribute__((amdgpu_flat_work_group_size(NTR, NTR),
                          amdgpu_waves_per_eu(1, 2)))
void k_run(const float* __restrict__ X,
           float* __restrict__ out,
           float* __restrict__ ws) {
    __shared__ __align__(16) float Dl[T_*PADK];
    __shared__ float SCM[2*KC][NTR];
    __shared__ float SCP[PASS ? 2*KC : 1][NTR];   // pass-0: no cp needed

    const int tid = threadIdx.x;
    for (int e = tid; e < T_*PADK; e += NTR) Dl[e] = ws[WS_D + e];
    const float Linv = ws[WS_LINV];
    __syncthreads();

    const int lane  = tid & 63;
    const int sub   = lane & 15;
    const int gw    = (int)blockIdx.x * (NTR/64) + (tid >> 6);
    const int colb  = gw*8 + (lane >> 4)*2;        // [0, 12800), 2 cols/thread
    const int n0    = colb / M_;
    const int m0    = colb - n0*M_;
    const int n1    = (colb+1) / M_;
    const int m1    = (colb+1) - n1*M_;
    const int kbase = sub * KC;                    // sub>=14 -> pad region
    const float* Y0 = X + n0*TM_ + m0;
    const float* Y1 = X + n1*TM_ + m1;

    float x[2][KC], y[2][KC];
    const float wlc = LAM_ * Linv;

    // ---- b = Linv * (D^T Ycol) -> bb (init-phase registers) ----
    {
        float bb[2][KC];
        #pragma unroll
        for (int j = 0; j < KC; ++j) { bb[0][j] = 0.f; bb[1][j] = 0.f; }
        #pragma unroll 2
        for (int t = 0; t < T_; ++t) {
            float yv0 = Y0[t*M_], yv1 = Y1[t*M_];
            const float4* dp = (const float4*)(Dl + t*PADK + kbase);
            float4 da[3] = {dp[0], dp[1], dp[2]};
            #pragma unroll
            for (int q = 0; q < 3; ++q) {
                bb[0][4*q+0] = fmaf(da[q].x, yv0, bb[0][4*q+0]);
                bb[0][4*q+1] = fmaf(da[q].y, yv0, bb[0][4*q+1]);
                bb[0][4*q+2] = fmaf(da[q].z, yv0, bb[0][4*q+2]);
                bb[0][4*q+3] = fmaf(da[q].w, yv0, bb[0][4*q+3]);
                bb[1][4*q+0] = fmaf(da[q].x, yv1, bb[1][4*q+0]);
                bb[1][4*q+1] = fmaf(da[q].y, yv1, bb[1][4*q+1]);
                bb[1][4*q+2] = fmaf(da[q].z, yv1, bb[1][4*q+2]);
                bb[1][4*q+3] = fmaf(da[q].w, yv1, bb[1][4*q+3]);
            }
        }
        #pragma unroll
        for (int j = 0; j < KC; ++j) { bb[0][j] *= Linv; bb[1][j] *= Linv; }

        if constexpr (PASS == 0) {
            #pragma unroll
            for (int c = 0; c < 2; ++c)
                #pragma unroll
                for (int j = 0; j < KC; ++j)
                    SCM[c*KC + j][tid] = bb[c][j];
        } else {
            // wl = K*lam*Linv/||wn|| * 1/(|x1|+0.01); SCM=b-wl, SCP=b+wl
            float scale = ((float)K_) * (LAM_ * Linv) / sqrtf(ws[WS_WN]);
            #pragma unroll
            for (int c = 0; c < 2; ++c) {
                const int nn = c ? n1 : n0, mm2 = c ? m1 : m0;
                #pragma unroll
                for (int j = 0; j < KC; ++j) {
                    int kg = kbase + j;
                    float x1 = (kg < K_) ? out[nn*KM_ + kg*M_ + mm2] : 0.f;
                    float wl = scale / (fabsf(x1) + 0.01f);
                    SCM[c*KC + j][tid] = bb[c][j] - wl;
                    SCP[c*KC + j][tid] = bb[c][j] + wl;
                }
            }
        }
    }
    __syncthreads();

    float tcur = 1.f;

    auto iterate = [&](float tt) -> float {
        float u[2][KC];
        #pragma unroll
        for (int j = 0; j < KC; ++j) { u[0][j] = 0.f; u[1][j] = 0.f; }
        #pragma unroll 2
        for (int t = 0; t < T_; ++t) {
            const float4* dp = (const float4*)(Dl + t*PADK + kbase);
            float4 da[3] = {dp[0], dp[1], dp[2]};
            float z00=0.f, z01=0.f, z02=0.f, z03=0.f;
            float z10=0.f, z11=0.f, z12=0.f, z13=0.f;
            #pragma unroll
            for (int q = 0; q < 3; ++q) {
                z00 = fmaf(da[q].x, y[0][4*q+0], z00);
                z01 = fmaf(da[q].y, y[0][4*q+1], z01);
                z02 = fmaf(da[q].z, y[0][4*q+2], z02);
                z03 = fmaf(da[q].w, y[0][4*q+3], z03);
                z10 = fmaf(da[q].x, y[1][4*q+0], z10);
                z11 = fmaf(da[q].y, y[1][4*q+1], z11);
                z12 = fmaf(da[q].z, y[1][4*q+2], z12);
                z13 = fmaf(da[q].w, y[1][4*q+3], z13);
            }
            float z0 = reduce16((z00+z01) + (z02+z03));   // 16 lanes hold z_t
            float z1 = reduce16((z10+z11) + (z12+z13));
            #pragma unroll
            for (int q = 0; q < 3; ++q) {
                u[0][4*q+0] = fmaf(da[q].x, z0, u[0][4*q+0]);
                u[0][4*q+1] = fmaf(da[q].y, z0, u[0][4*q+1]);
                u[0][4*q+2] = fmaf(da[q].z, z0, u[0][4*q+2]);
                u[0][4*q+3] = fmaf(da[q].w, z0, u[0][4*q+3]);
                u[1][4*q+0] = fmaf(da[q].x, z1, u[1][4*q+0]);
                u[1][4*q+1] = fmaf(da[q].y, z1, u[1][4*q+1]);
                u[1][4*q+2] = fmaf(da[q].z, z1, u[1][4*q+2]);
                u[1][4*q+3] = fmaf(da[q].w, z1, u[1][4*q+3]);
            }
        }
        float ss = 0.f;
        #pragma unroll
        for (int c = 0; c < 2; ++c) {
            #pragma unroll
            for (int j = 0; j < KC; ++j) {
                float v = fmaf(-Linv, u[c][j], y[c][j]);   // Ay
                float xn;
                if constexpr (PASS == 0) {
                    float s = v + SCM[c*KC + j][tid];       // Ay + b
                    xn = fmaxf(0.f, s - wlc) + fminf(0.f, s + wlc);
                } else {
                    xn = fmaxf(0.f, v + SCM[c*KC + j][tid])
                       + fminf(0.f, v + SCP[c*KC + j][tid]);
                }
                float d = xn - x[c][j];
                ss      = fmaf(d, d, ss);
                y[c][j] = fmaf(tt, d, xn);
                x[c][j] = xn;
            }
        }
        return ss;
    };

    #pragma unroll
    for (int j = 0; j < KC; ++j) {
        x[0][j] = 0.f; x[1][j] = 0.f; y[0][j] = 0.f; y[1][j] = 0.f;
    }
    float* acc = ws + WS_ACC + PASS*4*MAXIT;
    for (int i = 0; i < MAXIT; ++i) {
        float tnext = 0.5f * (1.f + sqrtf(fmaf(4.f*tcur, tcur, 1.f)));
        float tt = (tcur - 1.f) / tnext;
        tcur = tnext;
        float ss = iterate(tt);
        ss = reduce16(ss);                           // 4 DPP levels (VALU)
        ss += __shfl_xor(ss, 16);
        ss += __shfl_xor(ss, 32);
        if (lane == 0) atomicAdd(acc + i*4 + (gw & 3), ss);   // fire-and-forget
    }

    // ---- write code ----
    #pragma unroll
    for (int j = 0; j < KC; ++j) {
        int kg = kbase + j;
        if (kg < K_) {
            out[n0*KM_ + kg*M_ + m0] = x[0][j];
            out[n1*KM_ + kg*M_ + m1] = x[1][j];
        }
    }
}

// ---------------------------------------------------------------------------
// helpers for the (rarely-executed) replay/finish kernels (register version)
// ---------------------------------------------------------------------------
struct Geo { int n0, m0, n1, m1, kbase, sub, lane; };
__device__ __forceinline__ Geo make_geo() {
    Geo g;
    const int tid = threadIdx.x;
    g.lane = tid & 63;
    g.sub  = g.lane & 15;
    const int gw   = (int)blockIdx.x * (NTR/64) + (tid >> 6);
    const int colb = gw*8 + (g.lane >> 4)*2;
    g.n0 = colb / M_;       g.m0 = colb - g.n0*M_;
    g.n1 = (colb+1) / M_;   g.m1 = (colb+1) - g.n1*M_;
    g.kbase = g.sub * KC;
    return g;
}

__device__ __forceinline__ void compute_b(const float* Dl, int kbase, float Linv,
                                          const float* Y0, const float* Y1,
                                          float (&b)[2][KC]) {
    #pragma unroll
    for (int j = 0; j < KC; ++j) { b[0][j] = 0.f; b[1][j] = 0.f; }
    #pragma unroll 2
    for (int t = 0; t < T_; ++t) {
        float yv0 = Y0[t*M_], yv1 = Y1[t*M_];
        const float4* dp = (const float4*)(Dl + t*PADK + kbase);
        float4 da[3] = {dp[0], dp[1], dp[2]};
        #pragma unroll
        for (int q = 0; q < 3; ++q) {
            b[0][4*q+0] = fmaf(da[q].x, yv0, b[0][4*q+0]);
            b[0][4*q+1] = fmaf(da[q].y, yv0, b[0][4*q+1]);
            b[0][4*q+2] = fmaf(da[q].z, yv0, b[0][4*q+2]);
            b[0][4*q+3] = fmaf(da[q].w, yv0, b[0][4*q+3]);
            b[1][4*q+0] = fmaf(da[q].x, yv1, b[1][4*q+0]);
            b[1][4*q+1] = fmaf(da[q].y, yv1, b[1][4*q+1]);
            b[1][4*q+2] = fmaf(da[q].z, yv1, b[1][4*q+2]);
            b[1][4*q+3] = fmaf(da[q].w, yv1, b[1][4*q+3]);
        }
    }
    #pragma unroll
    for (int j = 0; j < KC; ++j) { b[0][j] *= Linv; b[1][j] *= Linv; }
}

__device__ __forceinline__ void run_fista(const float* Dl, int kbase, float Linv,
                                          const float (&cmv)[2][KC],
                                          const float (&cpv)[2][KC],
                                          float (&x)[2][KC], int nit) {
    float y[2][KC];
    #pragma unroll
    for (int j = 0; j < KC; ++j) {
        x[0][j] = 0.f; x[1][j] = 0.f; y[0][j] = 0.f; y[1][j] = 0.f;
    }
    float tcur = 1.f;
    for (int i = 0; i < nit; ++i) {
        float tnext = 0.5f * (1.f + sqrtf(fmaf(4.f*tcur, tcur, 1.f)));
        float tt = (tcur - 1.f) / tnext;
        tcur = tnext;
        float u[2][KC];
        #pragma unroll
        for (int j = 0; j < KC; ++j) { u[0][j] = 0.f; u[1][j] = 0.f; }
        #pragma unroll 2
        for (int t = 0; t < T_; ++t) {
            const float4* dp = (const float4*)(Dl + t*PADK + kbase);
            float4 da[3] = {dp[0], dp[1], dp[2]};
            float z00=0.f, z01=0.f, z02=0.f, z03=0.f;
            float z10=0.f, z11=0.f, z12=0.f, z13=0.f;
            #pragma unroll
            for (int q = 0; q < 3; ++q) {
                z00 = fmaf(da[q].x, y[0][4*q+0], z00);
                z01 = fmaf(da[q].y, y[0][4*q+1], z01);
                z02 = fmaf(da[q].z, y[0][4*q+2], z02);
                z03 = fmaf(da[q].w, y[0][4*q+3], z03);
                z10 = fmaf(da[q].x, y[1][4*q+0], z10);
                z11 = fmaf(da[q].y, y[1][4*q+1], z11);
                z12 = fmaf(da[q].z, y[1][4*q+2], z12);
                z13 = fmaf(da[q].w, y[1][4*q+3], z13);
            }
            float z0 = reduce16((z00+z01) + (z02+z03));
            float z1 = reduce16((z10+z11) + (z12+z13));
            #pragma unroll
            for (int q = 0; q < 3; ++q) {
                u[0][4*q+0] = fmaf(da[q].x, z0, u[0][4*q+0]);
                u[0][4*q+1] = fmaf(da[q].y, z0, u[0][4*q+1]);
                u[0][4*q+2] = fmaf(da[q].z, z0, u[0][4*q+2]);
                u[0][4*q+3] = fmaf(da[q].w, z0, u[0][4*q+3]);
                u[1][4*q+0] = fmaf(da[q].x, z1, u[1][4*q+0]);
                u[1][4*q+1] = fmaf(da[q].y, z1, u[1][4*q+1]);
                u[1][4*q+2] = fmaf(da[q].z, z1, u[1][4*q+2]);
                u[1][4*q+3] = fmaf(da[q].w, z1, u[1][4*q+3]);
            }
        }
        #pragma unroll
        for (int c = 0; c < 2; ++c) {
            #pragma unroll
            for (int j = 0; j < KC; ++j) {
                float v = fmaf(-Linv, u[c][j], y[c][j]);
                float xn = fmaxf(0.f, v + cmv[c][j]) + fminf(0.f, v + cpv[c][j]);
                float d = xn - x[c][j];
                y[c][j] = fmaf(tt, d, xn);
                x[c][j] = xn;
            }
        }
    }
}

__device__ __forceinline__ void write_code_g(const Geo& g, const float (&x)[2][KC],
                                             float* out) {
    #pragma unroll
    for (int j = 0; j < KC; ++j) {
        int kg = g.kbase + j;
        if (kg < K_) {
            out[g.n0*KM_ + kg*M_ + g.m0] = x[0][j];
            out[g.n1*KM_ + kg*M_ + g.m1] = x[1][j];
        }
    }
}
__device__ __forceinline__ void load_code_g(const Geo& g, float (&x)[2][KC],
                                            const float* out) {
    #pragma unroll
    for (int j = 0; j < KC; ++j) {
        int kg = g.kbase + j;
        x[0][j] = (kg < K_) ? out[g.n0*KM_ + kg*M_ + g.m0] : 0.f;
        x[1][j] = (kg < K_) ? out[g.n1*KM_ + kg*M_ + g.m1] : 0.f;
    }
}

// ---------------------------------------------------------------------------
// k_scan: find first iter with global ||dx||^2 < (tol*K)^2 (4 slots per iter)
// ---------------------------------------------------------------------------
__global__ void k_scan(float* __restrict__ ws, int pass) {
    const float THR2 = (1e-5f * (float)K_) * (1e-5f * (float)K_);
    int lane = threadIdx.x;
    const float* acc = ws + WS_ACC + pass*4*MAXIT;
    int best = MAXIT + 1;
    for (int i = lane; i < MAXIT; i += 64) {
        float a = (acc[i*4] + acc[i*4+1]) + (acc[i*4+2] + acc[i*4+3]);
        if (a < THR2) best = min(best, i + 1);
    }
    #pragma unroll
    for (int mm = 1; mm < 64; mm <<= 1) best = min(best, __shfl_xor(best, mm));
    if (lane == 0) ((int*)ws)[pass == 0 ? WS_NIT1 : WS_NIT2] = best;
}

// ---------------------------------------------------------------------------
// k_fin1: if pass-1 converged early, replay nit1 iters and rewrite code;
// then accumulate ||wn||^2 into WS_WN. (Expected: no replay -> cheap.)
// ---------------------------------------------------------------------------
__global__ __launch_bounds__(NTR, 1) void k_fin1(const float* __restrict__ X,
                                                 float* __restrict__ out,
                                                 float* __restrict__ ws) {
    __shared__ __align__(16) float Dl[T_*PADK];
    for (int e = threadIdx.x; e < T_*PADK; e += NTR) Dl[e] = ws[WS_D + e];
    const float Linv = ws[WS_LINV];
    __syncthreads();

    Geo g = make_geo();
    const int nit1 = ((const int*)ws)[WS_NIT1];
    float x[2][KC];

    if (nit1 <= MAXIT) {
        float b[2][KC], cmv[2][KC], cpv[2][KC];
        compute_b(Dl, g.kbase, Linv, X + g.n0*TM_ + g.m0, X + g.n1*TM_ + g.m1, b);
        const float wlc = LAM_ * Linv;
        #pragma unroll
        for (int c = 0; c < 2; ++c)
            #pragma unroll
            for (int j = 0; j < KC; ++j) { cmv[c][j] = b[c][j] - wlc;
                                           cpv[c][j] = b[c][j] + wlc; }
        run_fista(Dl, g.kbase, Linv, cmv, cpv, x, nit1);
        write_code_g(g, x, out);
    } else {
        load_code_g(g, x, out);
    }

    float loc = 0.f;
    #pragma unroll
    for (int c = 0; c < 2; ++c)
        #pragma unroll
        for (int j = 0; j < KC; ++j) {
            if (g.kbase + j < K_) {
                float wn = 1.0f / (fabsf(x[c][j]) + 0.01f);
                loc = fmaf(wn, wn, loc);
            }
        }
    #pragma unroll
    for (int mm = 1; mm < 64; mm <<= 1) loc += __shfl_xor(loc, mm);
    if (g.lane == 0) atomicAdd(ws + WS_WN, loc);
}

// ---------------------------------------------------------------------------
// k_fin2: if pass-2 converged early, re-derive pass-1 x, recompute weights,
// replay nit2 iters, rewrite code. Always write reconst from final code.
// ---------------------------------------------------------------------------
__global__ __launch_bounds__(NTR, 1) void k_fin2(const float* __restrict__ X,
                                                 float* __restrict__ out,
                                                 float* __restrict__ ws) {
    __shared__ __align__(16) float Dl[T_*PADK];
    for (int e = threadIdx.x; e < T_*PADK; e += NTR) Dl[e] = ws[WS_D + e];
    const float Linv = ws[WS_LINV];
    __syncthreads();

    Geo g = make_geo();
    const int nit1 = ((const int*)ws)[WS_NIT1];
    const int nit2 = ((const int*)ws)[WS_NIT2];
    float x[2][KC];

    if (nit2 <= MAXIT) {
        float b[2][KC], cmv[2][KC], cpv[2][KC];
        compute_b(Dl, g.kbase, Linv, X + g.n0*TM_ + g.m0, X + g.n1*TM_ + g.m1, b);
        const float wlc = LAM_ * Linv;
        #pragma unroll
        for (int c = 0; c < 2; ++c)
            #pragma unroll
            for (int j = 0; j < KC; ++j) { cmv[c][j] = b[c][j] - wlc;
                                           cpv[c][j] = b[c][j] + wlc; }
        int nrep1 = nit1 <= MAXIT ? nit1 : MAXIT;
        run_fista(Dl, g.kbase, Linv, cmv, cpv, x, nrep1);
        float scale = ((float)K_) * (LAM_ * Linv) / sqrtf(ws[WS_WN]);
        #pragma unroll
        for (int c = 0; c < 2; ++c)
            #pragma unroll
            for (int j = 0; j < KC; ++j) {
                float wl = scale / (fabsf(x[c][j]) + 0.01f);
                cmv[c][j] = b[c][j] - wl;
                cpv[c][j] = b[c][j] + wl;
            }
        run_fista(Dl, g.kbase, Linv, cmv, cpv, x, nit2);
        write_code_g(g, x, out);
    } else {
        load_code_g(g, x, out);
    }

    // ---- reconst = D @ code ----
    #pragma unroll 2
    for (int t = 0; t < T_; ++t) {
        const float4* dp = (const float4*)(Dl + t*PADK + g.kbase);
        float4 da[3] = {dp[0], dp[1], dp[2]};
        float z00=0.f, z01=0.f, z02=0.f, z03=0.f;
        float z10=0.f, z11=0.f, z12=0.f, z13=0.f;
        #pragma unroll
        for (int q = 0; q < 3; ++q) {
            z00 = fmaf(da[q].x, x[0][4*q+0], z00);
            z01 = fmaf(da[q].y, x[0][4*q+1], z01);
            z02 = fmaf(da[q].z, x[0][4*q+2], z02);
            z03 = fmaf(da[q].w, x[0][4*q+3], z03);
            z10 = fmaf(da[q].x, x[1][4*q+0], z10);
            z11 = fmaf(da[q].y, x[1][4*q+1], z11);
            z12 = fmaf(da[q].z, x[1][4*q+2], z12);
            z13 = fmaf(da[q].w, x[1][4*q+3], z13);
        }
        float z0 = reduce16((z00+z01) + (z02+z03));
        float z1 = reduce16((z10+z11) + (z12+z13));
        if (g.sub == (t & 15)) {
            out[OUT_REC + g.n0*TM_ + t*M_ + g.m0] = z0;
            out[OUT_REC + g.n1*TM_ + t*M_ + g.m1] = z1;
        }
    }
}

// ---------------------------------------------------------------------------
extern "C" void kernel_launch(void* const* d_in, const int* in_sizes, int n_in,
                              void* d_out, int out_size, void* d_ws, size_t ws_size,
                              hipStream_t stream) {
    const float* X  = (const float*)d_in[0];
    const float* rr = (const float*)d_in[1];
    const float* th = (const float*)d_in[2];
    float* out = (float*)d_out;
    float* ws  = (float*)d_ws;

    // zero conv accumulators + wn accumulator + niter slots (every call)
    hipMemsetAsync((char*)d_ws + WS_ACC*sizeof(float), 0, 4096, stream);
    k_dict  <<<dim3(1),   dim3(256), 0, stream>>>(rr, th, out, ws);
    k_run<0><<<dim3(NBR), dim3(NTR), 0, stream>>>(X, out, ws);
    k_scan  <<<dim3(1),   dim3(64),  0, stream>>>(ws, 0);
    k_fin1  <<<dim3(NBR), dim3(NTR), 0, stream>>>(X, out, ws);
    k_run<1><<<dim3(NBR), dim3(NTR), 0, stream>>>(X, out, ws);
    k_scan  <<<dim3(1),   dim3(64),  0, stream>>>(ws, 1);
    k_fin2  <<<dim3(NBR), dim3(NTR), 0, stream>>>(X, out, ws);
}

// Round 14
// 2128.728 us; speedup vs baseline: 1.1425x; 1.0017x over previous
//
#include <hip/hip_runtime.h>
#include <math.h>

// ---------------- problem constants (fixed by setup_inputs) ----------------
#define N_    256
#define T_    36
#define M_    50
#define P_    80
#define K_    161          // 1 + 2P
#define PADK  192          // K padded to 16*12, pad cols are zero
#define KC    12           // k-elements per lane (16 lanes per column)
#define NBR   800          // run-kernel blocks (2 waves each -> 1600 waves)
#define NTR   128          // 2 waves/block: wave-granular load balance
#define LAM_  0.1f
#define MAXIT 100

#define KM_     (K_*M_)        // 8050
#define TM_     (T_*M_)        // 1800
#define OUT_DIC 2060800        // N*K*M
#define OUT_REC 2066596        // + T*K

// ---- workspace float offsets ----
#define WS_LINV 0
#define WS_D    64             // 36*192 = 6912 floats
#define WS_ACC  8192           // 2 passes * 100 iters * 4 slots = 800 floats
#define WS_WN   9000           // 1 float (sum of wn^2 over pass-1 code)
#define WS_NIT1 9002           // int slot: pass-1 replay count (101 = none)
#define WS_NIT2 9003           // int slot: pass-2 replay count

// ---------------------------------------------------------------------------
// kernel 1: build dictionary (write dic output + padded D to ws) and
// Linv = 1/frob(DtD) using frob(DtD) == frob(D D^T)  (36x36 instead of 161^2)
// ---------------------------------------------------------------------------
__global__ __launch_bounds__(256) void k_dict(const float* __restrict__ rr,
                                              const float* __restrict__ th,
                                              float* __restrict__ out,
                                              float* __restrict__ ws) {
    __shared__ float Dl[T_*PADK];
    const int tid = threadIdx.x;
    for (int e = tid; e < T_*PADK; e += 256) {
        int t = e / PADK, k = e - (e / PADK) * PADK;
        float v = 0.f;
        if (k == 0) v = 1.f;
        else if (k <= P_)      { float r = rr[k-1];     float a = th[k-1]*(float)t;
                                 v = powf(r, (float)t) * cosf(a); }
        else if (k <= 2*P_)    { float r = rr[k-1-P_];  float a = th[k-1-P_]*(float)t;
                                 v = powf(r, (float)t) * sinf(a); }
        Dl[e] = v;
        ws[WS_D + e] = v;
        if (k < K_) out[OUT_DIC + t*K_ + k] = v;
    }
    __syncthreads();
    float loc = 0.f;
    for (int e = tid; e < T_*T_; e += 256) {
        int t1 = e / T_, t2 = e - (e / T_) * T_;
        float s = 0.f;
        for (int k = 0; k < K_; ++k) s = fmaf(Dl[t1*PADK+k], Dl[t2*PADK+k], s);
        loc = fmaf(s, s, loc);
    }
    #pragma unroll
    for (int mm = 1; mm < 64; mm <<= 1) loc += __shfl_xor(loc, mm);
    __shared__ float rb[4];
    if ((tid & 63) == 0) rb[tid >> 6] = loc;
    __syncthreads();
    if (tid == 0) {
        float tot = rb[0] + rb[1] + rb[2] + rb[3];
        ws[WS_LINV] = 1.0f / sqrtf(tot);
    }
}

// ---- DPP-based 16-lane sum (pure VALU, off the LDS pipe) -------------------
template<int CTRL>
__device__ __forceinline__ float dpp_mov(float v) {
    int p = __builtin_amdgcn_update_dpp(0, __float_as_int(v), CTRL, 0xF, 0xF, true);
    return __int_as_float(p);
}
__device__ __forceinline__ float reduce16(float z) {
    z += dpp_mov<0xB1>(z);     // quad_perm [1,0,3,2]  (xor 1)
    z += dpp_mov<0x4E>(z);     // quad_perm [2,3,0,1]  (xor 2)
    z += dpp_mov<0x141>(z);    // row_half_mirror      (other quad)
    z += dpp_mov<0x140>(z);    // row_mirror           (other 8-group)
    return z;
}

// ---------------------------------------------------------------------------
// k_run<PASS>: the r7 champion (C=2, KC=12, NTR=128) with waves_per_eu(1,1):
// knob trend r6 default->72 VGPR (heavy accvgpr churn), r7 (1,2)->88-108
// (less churn, 903us/pass). (1,1) removes the occupancy floor so the RA can
// hold all ~150 state floats in arch VGPRs; <=256 regs still leaves 2
// waves/SIMD possible (grid avg 1.56), so no occupancy loss vs r7.
// PASS 0: scalar wl = lam*Linv, state {x,y,b,u}.
// PASS 1: cm/cp = b -/+ wl(x1) precomputed, state {x,y,cm,cp,u}.
// ---------------------------------------------------------------------------
template<int PASS>
__global__ __attribute__((amdgpu_flat_work_group_size(NTR, NTR),
                          amdgpu_waves_per_eu(1, 1)))
void k_run(const float* __restrict__ X,
           float* __restrict__ out,
           float* __restrict__ ws) {
    __shared__ __align__(16) float Dl[T_*PADK];
    const int tid = threadIdx.x;
    for (int e = tid; e < T_*PADK; e += NTR) Dl[e] = ws[WS_D + e];
    const float Linv = ws[WS_LINV];
    __syncthreads();

    const int lane  = tid & 63;
    const int sub   = lane & 15;
    const int gw    = (int)blockIdx.x * (NTR/64) + (tid >> 6);
    const int colb  = gw*8 + (lane >> 4)*2;        // [0, 12800), 2 cols/thread
    const int n0    = colb / M_;
    const int m0    = colb - n0*M_;
    const int n1    = (colb+1) / M_;
    const int m1    = (colb+1) - n1*M_;
    const int kbase = sub * KC;                    // sub>=14 -> pad region
    const float* Y0 = X + n0*TM_ + m0;
    const float* Y1 = X + n1*TM_ + m1;

    float x[2][KC], y[2][KC], cm[2][KC], cp[2][KC];
    // cm/cp usage: PASS==0 -> cm = b (cp unused); PASS==1 -> cm/cp = b -/+ wl
    const float wlc = LAM_ * Linv;

    // ---- b = Linv * (D^T Ycol), stored into cm ----
    #pragma unroll
    for (int j = 0; j < KC; ++j) { cm[0][j] = 0.f; cm[1][j] = 0.f; }
    #pragma unroll 2
    for (int t = 0; t < T_; ++t) {
        float yv0 = Y0[t*M_], yv1 = Y1[t*M_];
        const float4* dp = (const float4*)(Dl + t*PADK + kbase);
        float4 da[3] = {dp[0], dp[1], dp[2]};
        #pragma unroll
        for (int q = 0; q < 3; ++q) {
            cm[0][4*q+0] = fmaf(da[q].x, yv0, cm[0][4*q+0]);
            cm[0][4*q+1] = fmaf(da[q].y, yv0, cm[0][4*q+1]);
            cm[0][4*q+2] = fmaf(da[q].z, yv0, cm[0][4*q+2]);
            cm[0][4*q+3] = fmaf(da[q].w, yv0, cm[0][4*q+3]);
            cm[1][4*q+0] = fmaf(da[q].x, yv1, cm[1][4*q+0]);
            cm[1][4*q+1] = fmaf(da[q].y, yv1, cm[1][4*q+1]);
            cm[1][4*q+2] = fmaf(da[q].z, yv1, cm[1][4*q+2]);
            cm[1][4*q+3] = fmaf(da[q].w, yv1, cm[1][4*q+3]);
        }
    }
    #pragma unroll
    for (int j = 0; j < KC; ++j) { cm[0][j] *= Linv; cm[1][j] *= Linv; }

    if (PASS == 1) {
        // wl = K*lam*Linv/||wn|| * 1/(|x1|+0.01); cm=b-wl, cp=b+wl
        float scale = ((float)K_) * (LAM_ * Linv) / sqrtf(ws[WS_WN]);
        #pragma unroll
        for (int c = 0; c < 2; ++c) {
            const int nn = c ? n1 : n0, mm2 = c ? m1 : m0;
            #pragma unroll
            for (int j = 0; j < KC; ++j) {
                int kg = kbase + j;
                float x1 = (kg < K_) ? out[nn*KM_ + kg*M_ + mm2] : 0.f;
                float wl = scale / (fabsf(x1) + 0.01f);
                float bb = cm[c][j];
                cm[c][j] = bb - wl;
                cp[c][j] = bb + wl;
            }
        }
    }

    float tcur = 1.f;

    auto iterate = [&](float tt) -> float {
        float u[2][KC];
        #pragma unroll
        for (int j = 0; j < KC; ++j) { u[0][j] = 0.f; u[1][j] = 0.f; }
        #pragma unroll 2
        for (int t = 0; t < T_; ++t) {
            const float4* dp = (const float4*)(Dl + t*PADK + kbase);
            float4 da[3] = {dp[0], dp[1], dp[2]};
            float z00=0.f, z01=0.f, z02=0.f, z03=0.f;
            float z10=0.f, z11=0.f, z12=0.f, z13=0.f;
            #pragma unroll
            for (int q = 0; q < 3; ++q) {
                z00 = fmaf(da[q].x, y[0][4*q+0], z00);
                z01 = fmaf(da[q].y, y[0][4*q+1], z01);
                z02 = fmaf(da[q].z, y[0][4*q+2], z02);
                z03 = fmaf(da[q].w, y[0][4*q+3], z03);
                z10 = fmaf(da[q].x, y[1][4*q+0], z10);
                z11 = fmaf(da[q].y, y[1][4*q+1], z11);
                z12 = fmaf(da[q].z, y[1][4*q+2], z12);
                z13 = fmaf(da[q].w, y[1][4*q+3], z13);
            }
            float z0 = reduce16((z00+z01) + (z02+z03));   // 16 lanes hold z_t
            float z1 = reduce16((z10+z11) + (z12+z13));
            #pragma unroll
            for (int q = 0; q < 3; ++q) {
                u[0][4*q+0] = fmaf(da[q].x, z0, u[0][4*q+0]);
                u[0][4*q+1] = fmaf(da[q].y, z0, u[0][4*q+1]);
                u[0][4*q+2] = fmaf(da[q].z, z0, u[0][4*q+2]);
                u[0][4*q+3] = fmaf(da[q].w, z0, u[0][4*q+3]);
                u[1][4*q+0] = fmaf(da[q].x, z1, u[1][4*q+0]);
                u[1][4*q+1] = fmaf(da[q].y, z1, u[1][4*q+1]);
                u[1][4*q+2] = fmaf(da[q].z, z1, u[1][4*q+2]);
                u[1][4*q+3] = fmaf(da[q].w, z1, u[1][4*q+3]);
            }
        }
        float ss = 0.f;
        #pragma unroll
        for (int c = 0; c < 2; ++c) {
            #pragma unroll
            for (int j = 0; j < KC; ++j) {
                float v = fmaf(-Linv, u[c][j], y[c][j]);   // Ay
                float xn;
                if (PASS == 0) {
                    float s = v + cm[c][j];                 // Ay + b
                    xn = fmaxf(0.f, s - wlc) + fminf(0.f, s + wlc);
                } else {
                    xn = fmaxf(0.f, v + cm[c][j]) + fminf(0.f, v + cp[c][j]);
                }
                float d = xn - x[c][j];
                ss      = fmaf(d, d, ss);
                y[c][j] = fmaf(tt, d, xn);
                x[c][j] = xn;
            }
        }
        return ss;
    };

    #pragma unroll
    for (int j = 0; j < KC; ++j) {
        x[0][j] = 0.f; x[1][j] = 0.f; y[0][j] = 0.f; y[1][j] = 0.f;
    }
    float* acc = ws + WS_ACC + PASS*4*MAXIT;
    for (int i = 0; i < MAXIT; ++i) {
        float tnext = 0.5f * (1.f + sqrtf(fmaf(4.f*tcur, tcur, 1.f)));
        float tt = (tcur - 1.f) / tnext;
        tcur = tnext;
        float ss = iterate(tt);
        ss = reduce16(ss);                           // 4 DPP levels (VALU)
        ss += __shfl_xor(ss, 16);
        ss += __shfl_xor(ss, 32);
        if (lane == 0) atomicAdd(acc + i*4 + (gw & 3), ss);   // fire-and-forget
    }

    // ---- write code ----
    #pragma unroll
    for (int j = 0; j < KC; ++j) {
        int kg = kbase + j;
        if (kg < K_) {
            out[n0*KM_ + kg*M_ + m0] = x[0][j];
            out[n1*KM_ + kg*M_ + m1] = x[1][j];
        }
    }
}

// ---------------------------------------------------------------------------
// helpers for the (rarely-executed) replay/finish kernels
// ---------------------------------------------------------------------------
struct Geo { int n0, m0, n1, m1, kbase, sub, lane; };
__device__ __forceinline__ Geo make_geo() {
    Geo g;
    const int tid = threadIdx.x;
    g.lane = tid & 63;
    g.sub  = g.lane & 15;
    const int gw   = (int)blockIdx.x * (NTR/64) + (tid >> 6);
    const int colb = gw*8 + (g.lane >> 4)*2;
    g.n0 = colb / M_;       g.m0 = colb - g.n0*M_;
    g.n1 = (colb+1) / M_;   g.m1 = (colb+1) - g.n1*M_;
    g.kbase = g.sub * KC;
    return g;
}

__device__ __forceinline__ void compute_b(const float* Dl, int kbase, float Linv,
                                          const float* Y0, const float* Y1,
                                          float (&b)[2][KC]) {
    #pragma unroll
    for (int j = 0; j < KC; ++j) { b[0][j] = 0.f; b[1][j] = 0.f; }
    #pragma unroll 2
    for (int t = 0; t < T_; ++t) {
        float yv0 = Y0[t*M_], yv1 = Y1[t*M_];
        const float4* dp = (const float4*)(Dl + t*PADK + kbase);
        float4 da[3] = {dp[0], dp[1], dp[2]};
        #pragma unroll
        for (int q = 0; q < 3; ++q) {
            b[0][4*q+0] = fmaf(da[q].x, yv0, b[0][4*q+0]);
            b[0][4*q+1] = fmaf(da[q].y, yv0, b[0][4*q+1]);
            b[0][4*q+2] = fmaf(da[q].z, yv0, b[0][4*q+2]);
            b[0][4*q+3] = fmaf(da[q].w, yv0, b[0][4*q+3]);
            b[1][4*q+0] = fmaf(da[q].x, yv1, b[1][4*q+0]);
            b[1][4*q+1] = fmaf(da[q].y, yv1, b[1][4*q+1]);
            b[1][4*q+2] = fmaf(da[q].z, yv1, b[1][4*q+2]);
            b[1][4*q+3] = fmaf(da[q].w, yv1, b[1][4*q+3]);
        }
    }
    #pragma unroll
    for (int j = 0; j < KC; ++j) { b[0][j] *= Linv; b[1][j] *= Linv; }
}

// generic FISTA run with per-element cm/cp (used only on replay paths)
__device__ __forceinline__ void run_fista(const float* Dl, int kbase, float Linv,
                                          const float (&cmv)[2][KC],
                                          const float (&cpv)[2][KC],
                                          float (&x)[2][KC], int nit) {
    float y[2][KC];
    #pragma unroll
    for (int j = 0; j < KC; ++j) {
        x[0][j] = 0.f; x[1][j] = 0.f; y[0][j] = 0.f; y[1][j] = 0.f;
    }
    float tcur = 1.f;
    for (int i = 0; i < nit; ++i) {
        float tnext = 0.5f * (1.f + sqrtf(fmaf(4.f*tcur, tcur, 1.f)));
        float tt = (tcur - 1.f) / tnext;
        tcur = tnext;
        float u[2][KC];
        #pragma unroll
        for (int j = 0; j < KC; ++j) { u[0][j] = 0.f; u[1][j] = 0.f; }
        #pragma unroll 2
        for (int t = 0; t < T_; ++t) {
            const float4* dp = (const float4*)(Dl + t*PADK + kbase);
            float4 da[3] = {dp[0], dp[1], dp[2]};
            float z00=0.f, z01=0.f, z02=0.f, z03=0.f;
            float z10=0.f, z11=0.f, z12=0.f, z13=0.f;
            #pragma unroll
            for (int q = 0; q < 3; ++q) {
                z00 = fmaf(da[q].x, y[0][4*q+0], z00);
                z01 = fmaf(da[q].y, y[0][4*q+1], z01);
                z02 = fmaf(da[q].z, y[0][4*q+2], z02);
                z03 = fmaf(da[q].w, y[0][4*q+3], z03);
                z10 = fmaf(da[q].x, y[1][4*q+0], z10);
                z11 = fmaf(da[q].y, y[1][4*q+1], z11);
                z12 = fmaf(da[q].z, y[1][4*q+2], z12);
                z13 = fmaf(da[q].w, y[1][4*q+3], z13);
            }
            float z0 = reduce16((z00+z01) + (z02+z03));
            float z1 = reduce16((z10+z11) + (z12+z13));
            #pragma unroll
            for (int q = 0; q < 3; ++q) {
                u[0][4*q+0] = fmaf(da[q].x, z0, u[0][4*q+0]);
                u[0][4*q+1] = fmaf(da[q].y, z0, u[0][4*q+1]);
                u[0][4*q+2] = fmaf(da[q].z, z0, u[0][4*q+2]);
                u[0][4*q+3] = fmaf(da[q].w, z0, u[0][4*q+3]);
                u[1][4*q+0] = fmaf(da[q].x, z1, u[1][4*q+0]);
                u[1][4*q+1] = fmaf(da[q].y, z1, u[1][4*q+1]);
                u[1][4*q+2] = fmaf(da[q].z, z1, u[1][4*q+2]);
                u[1][4*q+3] = fmaf(da[q].w, z1, u[1][4*q+3]);
            }
        }
        #pragma unroll
        for (int c = 0; c < 2; ++c) {
            #pragma unroll
            for (int j = 0; j < KC; ++j) {
                float v = fmaf(-Linv, u[c][j], y[c][j]);
                float xn = fmaxf(0.f, v + cmv[c][j]) + fminf(0.f, v + cpv[c][j]);
                float d = xn - x[c][j];
                y[c][j] = fmaf(tt, d, xn);
                x[c][j] = xn;
            }
        }
    }
}

__device__ __forceinline__ void write_code_g(const Geo& g, const float (&x)[2][KC],
                                             float* out) {
    #pragma unroll
    for (int j = 0; j < KC; ++j) {
        int kg = g.kbase + j;
        if (kg < K_) {
            out[g.n0*KM_ + kg*M_ + g.m0] = x[0][j];
            out[g.n1*KM_ + kg*M_ + g.m1] = x[1][j];
        }
    }
}
__device__ __forceinline__ void load_code_g(const Geo& g, float (&x)[2][KC],
                                            const float* out) {
    #pragma unroll
    for (int j = 0; j < KC; ++j) {
        int kg = g.kbase + j;
        x[0][j] = (kg < K_) ? out[g.n0*KM_ + kg*M_ + g.m0] : 0.f;
        x[1][j] = (kg < K_) ? out[g.n1*KM_ + kg*M_ + g.m1] : 0.f;
    }
}

// ---------------------------------------------------------------------------
// k_scan: find first iter with global ||dx||^2 < (tol*K)^2 (4 slots per iter)
// ---------------------------------------------------------------------------
__global__ void k_scan(float* __restrict__ ws, int pass) {
    const float THR2 = (1e-5f * (float)K_) * (1e-5f * (float)K_);
    int lane = threadIdx.x;
    const float* acc = ws + WS_ACC + pass*4*MAXIT;
    int best = MAXIT + 1;
    for (int i = lane; i < MAXIT; i += 64) {
        float a = (acc[i*4] + acc[i*4+1]) + (acc[i*4+2] + acc[i*4+3]);
        if (a < THR2) best = min(best, i + 1);
    }
    #pragma unroll
    for (int mm = 1; mm < 64; mm <<= 1) best = min(best, __shfl_xor(best, mm));
    if (lane == 0) ((int*)ws)[pass == 0 ? WS_NIT1 : WS_NIT2] = best;
}

// ---------------------------------------------------------------------------
// k_fin1: if pass-1 converged early, replay nit1 iters and rewrite code;
// then accumulate ||wn||^2 into WS_WN. (Expected: no replay -> cheap.)
// ---------------------------------------------------------------------------
__global__ __launch_bounds__(NTR, 1) void k_fin1(const float* __restrict__ X,
                                                 float* __restrict__ out,
                                                 float* __restrict__ ws) {
    __shared__ __align__(16) float Dl[T_*PADK];
    for (int e = threadIdx.x; e < T_*PADK; e += NTR) Dl[e] = ws[WS_D + e];
    const float Linv = ws[WS_LINV];
    __syncthreads();

    Geo g = make_geo();
    const int nit1 = ((const int*)ws)[WS_NIT1];
    float x[2][KC];

    if (nit1 <= MAXIT) {
        float b[2][KC], cmv[2][KC], cpv[2][KC];
        compute_b(Dl, g.kbase, Linv, X + g.n0*TM_ + g.m0, X + g.n1*TM_ + g.m1, b);
        const float wlc = LAM_ * Linv;
        #pragma unroll
        for (int c = 0; c < 2; ++c)
            #pragma unroll
            for (int j = 0; j < KC; ++j) { cmv[c][j] = b[c][j] - wlc;
                                           cpv[c][j] = b[c][j] + wlc; }
        run_fista(Dl, g.kbase, Linv, cmv, cpv, x, nit1);
        write_code_g(g, x, out);
    } else {
        load_code_g(g, x, out);
    }

    float loc = 0.f;
    #pragma unroll
    for (int c = 0; c < 2; ++c)
        #pragma unroll
        for (int j = 0; j < KC; ++j) {
            if (g.kbase + j < K_) {
                float wn = 1.0f / (fabsf(x[c][j]) + 0.01f);
                loc = fmaf(wn, wn, loc);
            }
        }
    #pragma unroll
    for (int mm = 1; mm < 64; mm <<= 1) loc += __shfl_xor(loc, mm);
    if (g.lane == 0) atomicAdd(ws + WS_WN, loc);
}

// ---------------------------------------------------------------------------
// k_fin2: if pass-2 converged early, re-derive pass-1 x, recompute weights,
// replay nit2 iters, rewrite code. Always write reconst from final code.
// ---------------------------------------------------------------------------
__global__ __launch_bounds__(NTR, 1) void k_fin2(const float* __restrict__ X,
                                                 float* __restrict__ out,
                                                 float* __restrict__ ws) {
    __shared__ __align__(16) float Dl[T_*PADK];
    for (int e = threadIdx.x; e < T_*PADK; e += NTR) Dl[e] = ws[WS_D + e];
    const float Linv = ws[WS_LINV];
    __syncthreads();

    Geo g = make_geo();
    const int nit1 = ((const int*)ws)[WS_NIT1];
    const int nit2 = ((const int*)ws)[WS_NIT2];
    float x[2][KC];

    if (nit2 <= MAXIT) {
        float b[2][KC], cmv[2][KC], cpv[2][KC];
        compute_b(Dl, g.kbase, Linv, X + g.n0*TM_ + g.m0, X + g.n1*TM_ + g.m1, b);
        const float wlc = LAM_ * Linv;
        #pragma unroll
        for (int c = 0; c < 2; ++c)
            #pragma unroll
            for (int j = 0; j < KC; ++j) { cmv[c][j] = b[c][j] - wlc;
                                           cpv[c][j] = b[c][j] + wlc; }
        int nrep1 = nit1 <= MAXIT ? nit1 : MAXIT;
        run_fista(Dl, g.kbase, Linv, cmv, cpv, x, nrep1);
        float scale = ((float)K_) * (LAM_ * Linv) / sqrtf(ws[WS_WN]);
        #pragma unroll
        for (int c = 0; c < 2; ++c)
            #pragma unroll
            for (int j = 0; j < KC; ++j) {
                float wl = scale / (fabsf(x[c][j]) + 0.01f);
                cmv[c][j] = b[c][j] - wl;
                cpv[c][j] = b[c][j] + wl;
            }
        run_fista(Dl, g.kbase, Linv, cmv, cpv, x, nit2);
        write_code_g(g, x, out);
    } else {
        load_code_g(g, x, out);
    }

    // ---- reconst = D @ code ----
    #pragma unroll 2
    for (int t = 0; t < T_; ++t) {
        const float4* dp = (const float4*)(Dl + t*PADK + g.kbase);
        float4 da[3] = {dp[0], dp[1], dp[2]};
        float z00=0.f, z01=0.f, z02=0.f, z03=0.f;
        float z10=0.f, z11=0.f, z12=0.f, z13=0.f;
        #pragma unroll
        for (int q = 0; q < 3; ++q) {
            z00 = fmaf(da[q].x, x[0][4*q+0], z00);
            z01 = fmaf(da[q].y, x[0][4*q+1], z01);
            z02 = fmaf(da[q].z, x[0][4*q+2], z02);
            z03 = fmaf(da[q].w, x[0][4*q+3], z03);
            z10 = fmaf(da[q].x, x[1][4*q+0], z10);
            z11 = fmaf(da[q].y, x[1][4*q+1], z11);
            z12 = fmaf(da[q].z, x[1][4*q+2], z12);
            z13 = fmaf(da[q].w, x[1][4*q+3], z13);
        }
        float z0 = reduce16((z00+z01) + (z02+z03));
        float z1 = reduce16((z10+z11) + (z12+z13));
        if (g.sub == (t & 15)) {
            out[OUT_REC + g.n0*TM_ + t*M_ + g.m0] = z0;
            out[OUT_REC + g.n1*TM_ + t*M_ + g.m1] = z1;
        }
    }
}

// ---------------------------------------------------------------------------
extern "C" void kernel_launch(void* const* d_in, const int* in_sizes, int n_in,
                              void* d_out, int out_size, void* d_ws, size_t ws_size,
                              hipStream_t stream) {
    const float* X  = (const float*)d_in[0];
    const float* rr = (const float*)d_in[1];
    const float* th = (const float*)d_in[2];
    float* out = (float*)d_out;
    float* ws  = (float*)d_ws;

    // zero conv accumulators + wn accumulator + niter slots (every call)
    hipMemsetAsync((char*)d_ws + WS_ACC*sizeof(float), 0, 4096, stream);
    k_dict  <<<dim3(1),   dim3(256), 0, stream>>>(rr, th, out, ws);
    k_run<0><<<dim3(NBR), dim3(NTR), 0, stream>>>(X, out, ws);
    k_scan  <<<dim3(1),   dim3(64),  0, stream>>>(ws, 0);
    k_fin1  <<<dim3(NBR), dim3(NTR), 0, stream>>>(X, out, ws);
    k_run<1><<<dim3(NBR), dim3(NTR), 0, stream>>>(X, out, ws);
    k_scan  <<<dim3(1),   dim3(64),  0, stream>>>(ws, 1);
    k_fin2  <<<dim3(NBR), dim3(NTR), 0, stream>>>(X, out, ws);
}

// Round 15
// 1791.970 us; speedup vs baseline: 1.3572x; 1.1879x over previous
//
#include <hip/hip_runtime.h>
#include <math.h>

// ---------------- problem constants (fixed by setup_inputs) ----------------
#define N_    256
#define T_    36
#define M_    50
#define P_    80
#define K_    161          // 1 + 2P
#define PADK  192          // K padded to 16*12, pad cols are zero
#define KC    12           // k-elements per lane (16 lanes per column)
#define NBR   800          // run-kernel blocks (2 waves each -> 1600 waves)
#define NTR   128          // 2 waves/block: wave-granular load balance
#define LAM_  0.1f
#define MAXIT 100

#define KM_     (K_*M_)        // 8050
#define TM_     (T_*M_)        // 1800
#define OUT_DIC 2060800        // N*K*M
#define OUT_REC 2066596        // + T*K

// ---- workspace float offsets ----
#define WS_LINV 0
#define WS_D    64             // 36*192 = 6912 floats
#define WS_ACC  8192           // 2 passes * 100 iters * 4 slots = 800 floats
#define WS_WN   9000           // 1 float (sum of wn^2 over pass-1 code)
#define WS_NIT1 9002           // int slot: pass-1 replay count (101 = none)
#define WS_NIT2 9003           // int slot: pass-2 replay count

// ---------------------------------------------------------------------------
// kernel 1: build dictionary (write dic output + padded D to ws) and
// Linv = 1/frob(DtD) using frob(DtD) == frob(D D^T)  (36x36 instead of 161^2)
// ---------------------------------------------------------------------------
__global__ __launch_bounds__(256) void k_dict(const float* __restrict__ rr,
                                              const float* __restrict__ th,
                                              float* __restrict__ out,
                                              float* __restrict__ ws) {
    __shared__ float Dl[T_*PADK];
    const int tid = threadIdx.x;
    for (int e = tid; e < T_*PADK; e += 256) {
        int t = e / PADK, k = e - (e / PADK) * PADK;
        float v = 0.f;
        if (k == 0) v = 1.f;
        else if (k <= P_)      { float r = rr[k-1];     float a = th[k-1]*(float)t;
                                 v = powf(r, (float)t) * cosf(a); }
        else if (k <= 2*P_)    { float r = rr[k-1-P_];  float a = th[k-1-P_]*(float)t;
                                 v = powf(r, (float)t) * sinf(a); }
        Dl[e] = v;
        ws[WS_D + e] = v;
        if (k < K_) out[OUT_DIC + t*K_ + k] = v;
    }
    __syncthreads();
    float loc = 0.f;
    for (int e = tid; e < T_*T_; e += 256) {
        int t1 = e / T_, t2 = e - (e / T_) * T_;
        float s = 0.f;
        for (int k = 0; k < K_; ++k) s = fmaf(Dl[t1*PADK+k], Dl[t2*PADK+k], s);
        loc = fmaf(s, s, loc);
    }
    #pragma unroll
    for (int mm = 1; mm < 64; mm <<= 1) loc += __shfl_xor(loc, mm);
    __shared__ float rb[4];
    if ((tid & 63) == 0) rb[tid >> 6] = loc;
    __syncthreads();
    if (tid == 0) {
        float tot = rb[0] + rb[1] + rb[2] + rb[3];
        ws[WS_LINV] = 1.0f / sqrtf(tot);
    }
}

// ---- DPP-based 16-lane sum (pure VALU, off the LDS pipe) -------------------
template<int CTRL>
__device__ __forceinline__ float dpp_mov(float v) {
    int p = __builtin_amdgcn_update_dpp(0, __float_as_int(v), CTRL, 0xF, 0xF, true);
    return __int_as_float(p);
}
__device__ __forceinline__ float reduce16(float z) {
    z += dpp_mov<0xB1>(z);     // quad_perm [1,0,3,2]  (xor 1)
    z += dpp_mov<0x4E>(z);     // quad_perm [2,3,0,1]  (xor 2)
    z += dpp_mov<0x141>(z);    // row_half_mirror      (other quad)
    z += dpp_mov<0x140>(z);    // row_mirror           (other 8-group)
    return z;
}

// ---------------------------------------------------------------------------
// k_run<PASS>: the measured champion (round 7): C=2, KC=12, NTR=128,
// waves_per_eu(1,2). Knob ledger (r6-r14): default->72VGPR/958us,
// (1,2)->88-108/903us BEST, (2,3)@256->68/1112, num_vgpr(128)->44/1188,
// (1,1)->132-but-occupancy-capped/1080. Structural alternatives (C=1,
// rotation, KC=6+pad, LDS-constants) all lost. Do not touch.
// PASS 0: scalar wl = lam*Linv, state {x,y,b,u}.
// PASS 1: cm/cp = b -/+ wl(x1) precomputed, state {x,y,cm,cp,u}.
// ---------------------------------------------------------------------------
template<int PASS>
__global__ __attribute__((amdgpu_flat_work_group_size(NTR, NTR),
                          amdgpu_waves_per_eu(1, 2)))
void k_run(const float* __restrict__ X,
           float* __restrict__ out,
           float* __restrict__ ws) {
    __shared__ __align__(16) float Dl[T_*PADK];
    const int tid = threadIdx.x;
    for (int e = tid; e < T_*PADK; e += NTR) Dl[e] = ws[WS_D + e];
    const float Linv = ws[WS_LINV];
    __syncthreads();

    const int lane  = tid & 63;
    const int sub   = lane & 15;
    const int gw    = (int)blockIdx.x * (NTR/64) + (tid >> 6);
    const int colb  = gw*8 + (lane >> 4)*2;        // [0, 12800), 2 cols/thread
    const int n0    = colb / M_;
    const int m0    = colb - n0*M_;
    const int n1    = (colb+1) / M_;
    const int m1    = (colb+1) - n1*M_;
    const int kbase = sub * KC;                    // sub>=14 -> pad region
    const float* Y0 = X + n0*TM_ + m0;
    const float* Y1 = X + n1*TM_ + m1;

    float x[2][KC], y[2][KC], cm[2][KC], cp[2][KC];
    // cm/cp usage: PASS==0 -> cm = b (cp unused); PASS==1 -> cm/cp = b -/+ wl
    const float wlc = LAM_ * Linv;

    // ---- b = Linv * (D^T Ycol), stored into cm ----
    #pragma unroll
    for (int j = 0; j < KC; ++j) { cm[0][j] = 0.f; cm[1][j] = 0.f; }
    #pragma unroll 2
    for (int t = 0; t < T_; ++t) {
        float yv0 = Y0[t*M_], yv1 = Y1[t*M_];
        const float4* dp = (const float4*)(Dl + t*PADK + kbase);
        float4 da[3] = {dp[0], dp[1], dp[2]};
        #pragma unroll
        for (int q = 0; q < 3; ++q) {
            cm[0][4*q+0] = fmaf(da[q].x, yv0, cm[0][4*q+0]);
            cm[0][4*q+1] = fmaf(da[q].y, yv0, cm[0][4*q+1]);
            cm[0][4*q+2] = fmaf(da[q].z, yv0, cm[0][4*q+2]);
            cm[0][4*q+3] = fmaf(da[q].w, yv0, cm[0][4*q+3]);
            cm[1][4*q+0] = fmaf(da[q].x, yv1, cm[1][4*q+0]);
            cm[1][4*q+1] = fmaf(da[q].y, yv1, cm[1][4*q+1]);
            cm[1][4*q+2] = fmaf(da[q].z, yv1, cm[1][4*q+2]);
            cm[1][4*q+3] = fmaf(da[q].w, yv1, cm[1][4*q+3]);
        }
    }
    #pragma unroll
    for (int j = 0; j < KC; ++j) { cm[0][j] *= Linv; cm[1][j] *= Linv; }

    if (PASS == 1) {
        // wl = K*lam*Linv/||wn|| * 1/(|x1|+0.01); cm=b-wl, cp=b+wl
        float scale = ((float)K_) * (LAM_ * Linv) / sqrtf(ws[WS_WN]);
        #pragma unroll
        for (int c = 0; c < 2; ++c) {
            const int nn = c ? n1 : n0, mm2 = c ? m1 : m0;
            #pragma unroll
            for (int j = 0; j < KC; ++j) {
                int kg = kbase + j;
                float x1 = (kg < K_) ? out[nn*KM_ + kg*M_ + mm2] : 0.f;
                float wl = scale / (fabsf(x1) + 0.01f);
                float bb = cm[c][j];
                cm[c][j] = bb - wl;
                cp[c][j] = bb + wl;
            }
        }
    }

    float tcur = 1.f;

    auto iterate = [&](float tt) -> float {
        float u[2][KC];
        #pragma unroll
        for (int j = 0; j < KC; ++j) { u[0][j] = 0.f; u[1][j] = 0.f; }
        #pragma unroll 2
        for (int t = 0; t < T_; ++t) {
            const float4* dp = (const float4*)(Dl + t*PADK + kbase);
            float4 da[3] = {dp[0], dp[1], dp[2]};
            float z00=0.f, z01=0.f, z02=0.f, z03=0.f;
            float z10=0.f, z11=0.f, z12=0.f, z13=0.f;
            #pragma unroll
            for (int q = 0; q < 3; ++q) {
                z00 = fmaf(da[q].x, y[0][4*q+0], z00);
                z01 = fmaf(da[q].y, y[0][4*q+1], z01);
                z02 = fmaf(da[q].z, y[0][4*q+2], z02);
                z03 = fmaf(da[q].w, y[0][4*q+3], z03);
                z10 = fmaf(da[q].x, y[1][4*q+0], z10);
                z11 = fmaf(da[q].y, y[1][4*q+1], z11);
                z12 = fmaf(da[q].z, y[1][4*q+2], z12);
                z13 = fmaf(da[q].w, y[1][4*q+3], z13);
            }
            float z0 = reduce16((z00+z01) + (z02+z03));   // 16 lanes hold z_t
            float z1 = reduce16((z10+z11) + (z12+z13));
            #pragma unroll
            for (int q = 0; q < 3; ++q) {
                u[0][4*q+0] = fmaf(da[q].x, z0, u[0][4*q+0]);
                u[0][4*q+1] = fmaf(da[q].y, z0, u[0][4*q+1]);
                u[0][4*q+2] = fmaf(da[q].z, z0, u[0][4*q+2]);
                u[0][4*q+3] = fmaf(da[q].w, z0, u[0][4*q+3]);
                u[1][4*q+0] = fmaf(da[q].x, z1, u[1][4*q+0]);
                u[1][4*q+1] = fmaf(da[q].y, z1, u[1][4*q+1]);
                u[1][4*q+2] = fmaf(da[q].z, z1, u[1][4*q+2]);
                u[1][4*q+3] = fmaf(da[q].w, z1, u[1][4*q+3]);
            }
        }
        float ss = 0.f;
        #pragma unroll
        for (int c = 0; c < 2; ++c) {
            #pragma unroll
            for (int j = 0; j < KC; ++j) {
                float v = fmaf(-Linv, u[c][j], y[c][j]);   // Ay
                float xn;
                if (PASS == 0) {
                    float s = v + cm[c][j];                 // Ay + b
                    xn = fmaxf(0.f, s - wlc) + fminf(0.f, s + wlc);
                } else {
                    xn = fmaxf(0.f, v + cm[c][j]) + fminf(0.f, v + cp[c][j]);
                }
                float d = xn - x[c][j];
                ss      = fmaf(d, d, ss);
                y[c][j] = fmaf(tt, d, xn);
                x[c][j] = xn;
            }
        }
        return ss;
    };

    #pragma unroll
    for (int j = 0; j < KC; ++j) {
        x[0][j] = 0.f; x[1][j] = 0.f; y[0][j] = 0.f; y[1][j] = 0.f;
    }
    float* acc = ws + WS_ACC + PASS*4*MAXIT;
    for (int i = 0; i < MAXIT; ++i) {
        float tnext = 0.5f * (1.f + sqrtf(fmaf(4.f*tcur, tcur, 1.f)));
        float tt = (tcur - 1.f) / tnext;
        tcur = tnext;
        float ss = iterate(tt);
        ss = reduce16(ss);                           // 4 DPP levels (VALU)
        ss += __shfl_xor(ss, 16);
        ss += __shfl_xor(ss, 32);
        if (lane == 0) atomicAdd(acc + i*4 + (gw & 3), ss);   // fire-and-forget
    }

    // ---- write code ----
    #pragma unroll
    for (int j = 0; j < KC; ++j) {
        int kg = kbase + j;
        if (kg < K_) {
            out[n0*KM_ + kg*M_ + m0] = x[0][j];
            out[n1*KM_ + kg*M_ + m1] = x[1][j];
        }
    }
}

// ---------------------------------------------------------------------------
// helpers for the (rarely-executed) replay/finish kernels
// ---------------------------------------------------------------------------
struct Geo { int n0, m0, n1, m1, kbase, sub, lane; };
__device__ __forceinline__ Geo make_geo() {
    Geo g;
    const int tid = threadIdx.x;
    g.lane = tid & 63;
    g.sub  = g.lane & 15;
    const int gw   = (int)blockIdx.x * (NTR/64) + (tid >> 6);
    const int colb = gw*8 + (g.lane >> 4)*2;
    g.n0 = colb / M_;       g.m0 = colb - g.n0*M_;
    g.n1 = (colb+1) / M_;   g.m1 = (colb+1) - g.n1*M_;
    g.kbase = g.sub * KC;
    return g;
}

__device__ __forceinline__ void compute_b(const float* Dl, int kbase, float Linv,
                                          const float* Y0, const float* Y1,
                                          float (&b)[2][KC]) {
    #pragma unroll
    for (int j = 0; j < KC; ++j) { b[0][j] = 0.f; b[1][j] = 0.f; }
    #pragma unroll 2
    for (int t = 0; t < T_; ++t) {
        float yv0 = Y0[t*M_], yv1 = Y1[t*M_];
        const float4* dp = (const float4*)(Dl + t*PADK + kbase);
        float4 da[3] = {dp[0], dp[1], dp[2]};
        #pragma unroll
        for (int q = 0; q < 3; ++q) {
            b[0][4*q+0] = fmaf(da[q].x, yv0, b[0][4*q+0]);
            b[0][4*q+1] = fmaf(da[q].y, yv0, b[0][4*q+1]);
            b[0][4*q+2] = fmaf(da[q].z, yv0, b[0][4*q+2]);
            b[0][4*q+3] = fmaf(da[q].w, yv0, b[0][4*q+3]);
            b[1][4*q+0] = fmaf(da[q].x, yv1, b[1][4*q+0]);
            b[1][4*q+1] = fmaf(da[q].y, yv1, b[1][4*q+1]);
            b[1][4*q+2] = fmaf(da[q].z, yv1, b[1][4*q+2]);
            b[1][4*q+3] = fmaf(da[q].w, yv1, b[1][4*q+3]);
        }
    }
    #pragma unroll
    for (int j = 0; j < KC; ++j) { b[0][j] *= Linv; b[1][j] *= Linv; }
}

// generic FISTA run with per-element cm/cp (used only on replay paths)
__device__ __forceinline__ void run_fista(const float* Dl, int kbase, float Linv,
                                          const float (&cmv)[2][KC],
                                          const float (&cpv)[2][KC],
                                          float (&x)[2][KC], int nit) {
    float y[2][KC];
    #pragma unroll
    for (int j = 0; j < KC; ++j) {
        x[0][j] = 0.f; x[1][j] = 0.f; y[0][j] = 0.f; y[1][j] = 0.f;
    }
    float tcur = 1.f;
    for (int i = 0; i < nit; ++i) {
        float tnext = 0.5f * (1.f + sqrtf(fmaf(4.f*tcur, tcur, 1.f)));
        float tt = (tcur - 1.f) / tnext;
        tcur = tnext;
        float u[2][KC];
        #pragma unroll
        for (int j = 0; j < KC; ++j) { u[0][j] = 0.f; u[1][j] = 0.f; }
        #pragma unroll 2
        for (int t = 0; t < T_; ++t) {
            const float4* dp = (const float4*)(Dl + t*PADK + kbase);
            float4 da[3] = {dp[0], dp[1], dp[2]};
            float z00=0.f, z01=0.f, z02=0.f, z03=0.f;
            float z10=0.f, z11=0.f, z12=0.f, z13=0.f;
            #pragma unroll
            for (int q = 0; q < 3; ++q) {
                z00 = fmaf(da[q].x, y[0][4*q+0], z00);
                z01 = fmaf(da[q].y, y[0][4*q+1], z01);
                z02 = fmaf(da[q].z, y[0][4*q+2], z02);
                z03 = fmaf(da[q].w, y[0][4*q+3], z03);
                z10 = fmaf(da[q].x, y[1][4*q+0], z10);
                z11 = fmaf(da[q].y, y[1][4*q+1], z11);
                z12 = fmaf(da[q].z, y[1][4*q+2], z12);
                z13 = fmaf(da[q].w, y[1][4*q+3], z13);
            }
            float z0 = reduce16((z00+z01) + (z02+z03));
            float z1 = reduce16((z10+z11) + (z12+z13));
            #pragma unroll
            for (int q = 0; q < 3; ++q) {
                u[0][4*q+0] = fmaf(da[q].x, z0, u[0][4*q+0]);
                u[0][4*q+1] = fmaf(da[q].y, z0, u[0][4*q+1]);
                u[0][4*q+2] = fmaf(da[q].z, z0, u[0][4*q+2]);
                u[0][4*q+3] = fmaf(da[q].w, z0, u[0][4*q+3]);
                u[1][4*q+0] = fmaf(da[q].x, z1, u[1][4*q+0]);
                u[1][4*q+1] = fmaf(da[q].y, z1, u[1][4*q+1]);
                u[1][4*q+2] = fmaf(da[q].z, z1, u[1][4*q+2]);
                u[1][4*q+3] = fmaf(da[q].w, z1, u[1][4*q+3]);
            }
        }
        #pragma unroll
        for (int c = 0; c < 2; ++c) {
            #pragma unroll
            for (int j = 0; j < KC; ++j) {
                float v = fmaf(-Linv, u[c][j], y[c][j]);
                float xn = fmaxf(0.f, v + cmv[c][j]) + fminf(0.f, v + cpv[c][j]);
                float d = xn - x[c][j];
                y[c][j] = fmaf(tt, d, xn);
                x[c][j] = xn;
            }
        }
    }
}

__device__ __forceinline__ void write_code_g(const Geo& g, const float (&x)[2][KC],
                                             float* out) {
    #pragma unroll
    for (int j = 0; j < KC; ++j) {
        int kg = g.kbase + j;
        if (kg < K_) {
            out[g.n0*KM_ + kg*M_ + g.m0] = x[0][j];
            out[g.n1*KM_ + kg*M_ + g.m1] = x[1][j];
        }
    }
}
__device__ __forceinline__ void load_code_g(const Geo& g, float (&x)[2][KC],
                                            const float* out) {
    #pragma unroll
    for (int j = 0; j < KC; ++j) {
        int kg = g.kbase + j;
        x[0][j] = (kg < K_) ? out[g.n0*KM_ + kg*M_ + g.m0] : 0.f;
        x[1][j] = (kg < K_) ? out[g.n1*KM_ + kg*M_ + g.m1] : 0.f;
    }
}

// ---------------------------------------------------------------------------
// k_scan: find first iter with global ||dx||^2 < (tol*K)^2 (4 slots per iter)
// ---------------------------------------------------------------------------
__global__ void k_scan(float* __restrict__ ws, int pass) {
    const float THR2 = (1e-5f * (float)K_) * (1e-5f * (float)K_);
    int lane = threadIdx.x;
    const float* acc = ws + WS_ACC + pass*4*MAXIT;
    int best = MAXIT + 1;
    for (int i = lane; i < MAXIT; i += 64) {
        float a = (acc[i*4] + acc[i*4+1]) + (acc[i*4+2] + acc[i*4+3]);
        if (a < THR2) best = min(best, i + 1);
    }
    #pragma unroll
    for (int mm = 1; mm < 64; mm <<= 1) best = min(best, __shfl_xor(best, mm));
    if (lane == 0) ((int*)ws)[pass == 0 ? WS_NIT1 : WS_NIT2] = best;
}

// ---------------------------------------------------------------------------
// k_fin1: if pass-1 converged early, replay nit1 iters and rewrite code;
// then accumulate ||wn||^2 into WS_WN. (Expected: no replay -> cheap.)
// ---------------------------------------------------------------------------
__global__ __launch_bounds__(NTR, 1) void k_fin1(const float* __restrict__ X,
                                                 float* __restrict__ out,
                                                 float* __restrict__ ws) {
    __shared__ __align__(16) float Dl[T_*PADK];
    for (int e = threadIdx.x; e < T_*PADK; e += NTR) Dl[e] = ws[WS_D + e];
    const float Linv = ws[WS_LINV];
    __syncthreads();

    Geo g = make_geo();
    const int nit1 = ((const int*)ws)[WS_NIT1];
    float x[2][KC];

    if (nit1 <= MAXIT) {
        float b[2][KC], cmv[2][KC], cpv[2][KC];
        compute_b(Dl, g.kbase, Linv, X + g.n0*TM_ + g.m0, X + g.n1*TM_ + g.m1, b);
        const float wlc = LAM_ * Linv;
        #pragma unroll
        for (int c = 0; c < 2; ++c)
            #pragma unroll
            for (int j = 0; j < KC; ++j) { cmv[c][j] = b[c][j] - wlc;
                                           cpv[c][j] = b[c][j] + wlc; }
        run_fista(Dl, g.kbase, Linv, cmv, cpv, x, nit1);
        write_code_g(g, x, out);
    } else {
        load_code_g(g, x, out);
    }

    float loc = 0.f;
    #pragma unroll
    for (int c = 0; c < 2; ++c)
        #pragma unroll
        for (int j = 0; j < KC; ++j) {
            if (g.kbase + j < K_) {
                float wn = 1.0f / (fabsf(x[c][j]) + 0.01f);
                loc = fmaf(wn, wn, loc);
            }
        }
    #pragma unroll
    for (int mm = 1; mm < 64; mm <<= 1) loc += __shfl_xor(loc, mm);
    if (g.lane == 0) atomicAdd(ws + WS_WN, loc);
}

// ---------------------------------------------------------------------------
// k_fin2: if pass-2 converged early, re-derive pass-1 x, recompute weights,
// replay nit2 iters, rewrite code. Always write reconst from final code.
// ---------------------------------------------------------------------------
__global__ __launch_bounds__(NTR, 1) void k_fin2(const float* __restrict__ X,
                                                 float* __restrict__ out,
                                                 float* __restrict__ ws) {
    __shared__ __align__(16) float Dl[T_*PADK];
    for (int e = threadIdx.x; e < T_*PADK; e += NTR) Dl[e] = ws[WS_D + e];
    const float Linv = ws[WS_LINV];
    __syncthreads();

    Geo g = make_geo();
    const int nit1 = ((const int*)ws)[WS_NIT1];
    const int nit2 = ((const int*)ws)[WS_NIT2];
    float x[2][KC];

    if (nit2 <= MAXIT) {
        float b[2][KC], cmv[2][KC], cpv[2][KC];
        compute_b(Dl, g.kbase, Linv, X + g.n0*TM_ + g.m0, X + g.n1*TM_ + g.m1, b);
        const float wlc = LAM_ * Linv;
        #pragma unroll
        for (int c = 0; c < 2; ++c)
            #pragma unroll
            for (int j = 0; j < KC; ++j) { cmv[c][j] = b[c][j] - wlc;
                                           cpv[c][j] = b[c][j] + wlc; }
        int nrep1 = nit1 <= MAXIT ? nit1 : MAXIT;
        run_fista(Dl, g.kbase, Linv, cmv, cpv, x, nrep1);
        float scale = ((float)K_) * (LAM_ * Linv) / sqrtf(ws[WS_WN]);
        #pragma unroll
        for (int c = 0; c < 2; ++c)
            #pragma unroll
            for (int j = 0; j < KC; ++j) {
                float wl = scale / (fabsf(x[c][j]) + 0.01f);
                cmv[c][j] = b[c][j] - wl;
                cpv[c][j] = b[c][j] + wl;
            }
        run_fista(Dl, g.kbase, Linv, cmv, cpv, x, nit2);
        write_code_g(g, x, out);
    } else {
        load_code_g(g, x, out);
    }

    // ---- reconst = D @ code ----
    #pragma unroll 2
    for (int t = 0; t < T_; ++t) {
        const float4* dp = (const float4*)(Dl + t*PADK + g.kbase);
        float4 da[3] = {dp[0], dp[1], dp[2]};
        float z00=0.f, z01=0.f, z02=0.f, z03=0.f;
        float z10=0.f, z11=0.f, z12=0.f, z13=0.f;
        #pragma unroll
        for (int q = 0; q < 3; ++q) {
            z00 = fmaf(da[q].x, x[0][4*q+0], z00);
            z01 = fmaf(da[q].y, x[0][4*q+1], z01);
            z02 = fmaf(da[q].z, x[0][4*q+2], z02);
            z03 = fmaf(da[q].w, x[0][4*q+3], z03);
            z10 = fmaf(da[q].x, x[1][4*q+0], z10);
            z11 = fmaf(da[q].y, x[1][4*q+1], z11);
            z12 = fmaf(da[q].z, x[1][4*q+2], z12);
            z13 = fmaf(da[q].w, x[1][4*q+3], z13);
        }
        float z0 = reduce16((z00+z01) + (z02+z03));
        float z1 = reduce16((z10+z11) + (z12+z13));
        if (g.sub == (t & 15)) {
            out[OUT_REC + g.n0*TM_ + t*M_ + g.m0] = z0;
            out[OUT_REC + g.n1*TM_ + t*M_ + g.m1] = z1;
        }
    }
}

// ---------------------------------------------------------------------------
extern "C" void kernel_launch(void* const* d_in, const int* in_sizes, int n_in,
                              void* d_out, int out_size, void* d_ws, size_t ws_size,
                              hipStream_t stream) {
    const float* X  = (const float*)d_in[0];
    const float* rr = (const float*)d_in[1];
    const float* th = (const float*)d_in[2];
    float* out = (float*)d_out;
    float* ws  = (float*)d_ws;

    // zero conv accumulators + wn accumulator + niter slots (every call)
    hipMemsetAsync((char*)d_ws + WS_ACC*sizeof(float), 0, 4096, stream);
    k_dict  <<<dim3(1),   dim3(256), 0, stream>>>(rr, th, out, ws);
    k_run<0><<<dim3(NBR), dim3(NTR), 0, stream>>>(X, out, ws);
    k_scan  <<<dim3(1),   dim3(64),  0, stream>>>(ws, 0);
    k_fin1  <<<dim3(NBR), dim3(NTR), 0, stream>>>(X, out, ws);
    k_run<1><<<dim3(NBR), dim3(NTR), 0, stream>>>(X, out, ws);
    k_scan  <<<dim3(1),   dim3(64),  0, stream>>>(ws, 1);
    k_fin2  <<<dim3(NBR), dim3(NTR), 0, stream>>>(X, out, ws);
}